// Round 11
// baseline (207.012 us; speedup 1.0000x reference)
//
#include <hip/hip_runtime.h>
#include <hip/hip_bf16.h>

#define DEVI __device__ __forceinline__

using u16 = unsigned short;
typedef __attribute__((ext_vector_type(8))) short bf16x8;
typedef __attribute__((ext_vector_type(4))) short bf16x4;
typedef __attribute__((ext_vector_type(4))) float f32x4;

constexpr int Bb = 4, Ls = 2048, Dd = 1024, Hh = 16, DhC = 64;
constexpr int Mm = Bb * Ls; // 8192

DEVI u16 f2bf(float f) {
  union { float f; unsigned u; } x; x.f = f;
  unsigned r = x.u + 0x7FFFu + ((x.u >> 16) & 1u);
  return (u16)(r >> 16);
}
DEVI float bf2f(u16 b) {
  union { unsigned u; float f; } x; x.u = ((unsigned)b) << 16;
  return x.f;
}

// pack two f32 -> two bf16 (RTNE): D[15:0]=bf16(a), D[31:16]=bf16(b)
DEVI unsigned cvt_pk_bf16(float a, float b) {
  unsigned d;
  asm("v_cvt_pk_bf16_f32 %0, %1, %2" : "=v"(d) : "v"(a), "v"(b));
  return d;
}

DEVI void gload_lds16(const u16* g, u16* l) {
  __builtin_amdgcn_global_load_lds(
      (const __attribute__((address_space(1))) unsigned int*)g,
      (__attribute__((address_space(3))) unsigned int*)l, 16, 0, 0);
}

DEVI bf16x8 ld_frag(const u16* p) { return *reinterpret_cast<const bf16x8*>(p); }

// single launch: x (8192x1024) + all four 1024x1024 weights
__global__ void cvt_all(const float* __restrict__ x,
                        const float* __restrict__ wq, const float* __restrict__ wk,
                        const float* __restrict__ wv, const float* __restrict__ wo,
                        u16* __restrict__ xb,
                        u16* __restrict__ wqb, u16* __restrict__ wkb,
                        u16* __restrict__ wvb, u16* __restrict__ wob) {
  const int tid = blockIdx.x * blockDim.x + threadIdx.x;  // grid 2048 x 256
  constexpr int NT = 2048 * 256;
  constexpr int N4X = Mm * Dd / 4;       // 2M float4
  constexpr int N4W = Dd * Dd / 4;       // 256K float4 per weight
  for (int i = tid; i < N4X; i += NT) {
    float4 v = reinterpret_cast<const float4*>(x)[i];
    reinterpret_cast<ushort4*>(xb)[i] =
        make_ushort4(f2bf(v.x), f2bf(v.y), f2bf(v.z), f2bf(v.w));
  }
  for (int i = tid; i < 4 * N4W; i += NT) {
    int which = i / N4W, off = i - which * N4W;
    const float* s = which == 0 ? wq : which == 1 ? wk : which == 2 ? wv : wo;
    u16* d = which == 0 ? wqb : which == 1 ? wkb : which == 2 ? wvb : wob;
    float4 v = reinterpret_cast<const float4*>(s)[off];
    reinterpret_cast<ushort4*>(d)[off] =
        make_ushort4(f2bf(v.x), f2bf(v.y), f2bf(v.z), f2bf(v.w));
  }
}

// Fused QKV projection: A (8192x1024) @ W^T where W = [wq;wk;wv] (3072x1024,
// contiguous in ws). Region 0/1 (q,k) written row-major; region 2 (v) written
// transposed (vt[dh][m]) so attention stages V^T directly.
__global__ __launch_bounds__(256) void gemm_qkv(
    const u16* __restrict__ A, const u16* __restrict__ W,
    const float* __restrict__ bq, const float* __restrict__ bk2,
    const float* __restrict__ bv,
    u16* __restrict__ qm, u16* __restrict__ km, u16* __restrict__ vt)
{
  constexpr int BK = 64, K = 1024;
  __shared__ u16 As[128 * BK];
  __shared__ u16 Bs[128 * BK];
  const int tid = threadIdx.x;
  const int wave = tid >> 6, lane = tid & 63;
  const int wr = wave >> 1, wc = wave & 1;
  const int lrow = lane & 15, lk = (lane >> 4) * 8;
  const int m0 = blockIdx.y * 128;
  const int n0g = blockIdx.x * 128;           // global n in [0,3072)
  const int srow = lane >> 3, scol = (lane & 7) * 8;

  f32x4 acc[4][4] = {};

  for (int k0 = 0; k0 < K; k0 += BK) {
    __syncthreads();
#pragma unroll
    for (int i = 0; i < 4; ++i) {
      int g = wave * 4 + i;
      int row = g * 8 + srow;
      gload_lds16(A + (size_t)(m0 + row) * K + k0 + scol, As + g * 512);
      gload_lds16(W + (size_t)(n0g + row) * K + k0 + scol, Bs + g * 512);
    }
    __syncthreads();
#pragma unroll
    for (int kk = 0; kk < 2; ++kk) {
      bf16x8 af[4], bfr[4];
#pragma unroll
      for (int m = 0; m < 4; ++m) af[m]  = ld_frag(As + (wr*64 + m*16 + lrow)*BK + kk*32 + lk);
#pragma unroll
      for (int n = 0; n < 4; ++n) bfr[n] = ld_frag(Bs + (wc*64 + n*16 + lrow)*BK + kk*32 + lk);
      __builtin_amdgcn_s_setprio(1);
#pragma unroll
      for (int m = 0; m < 4; ++m)
#pragma unroll
        for (int n = 0; n < 4; ++n)
          acc[m][n] = __builtin_amdgcn_mfma_f32_16x16x32_bf16(af[m], bfr[n], acc[m][n], 0, 0, 0);
      __builtin_amdgcn_s_setprio(0);
    }
  }

  const int region = blockIdx.x >> 3;         // 0=q, 1=k, 2=v
  const int nc0 = (blockIdx.x & 7) * 128;     // n within the 1024 region
  const float* bias = region == 0 ? bq : region == 1 ? bk2 : bv;
  u16* dstRM = region == 0 ? qm : km;

#pragma unroll
  for (int m = 0; m < 4; ++m) {
#pragma unroll
    for (int n = 0; n < 4; ++n) {
      int row = m0 + wr*64 + m*16 + (lane >> 4) * 4;
      int col = nc0 + wc*64 + n*16 + lrow;
      float bv_ = bias[col];
      if (region == 2) {
        ushort4 o;
        o.x = f2bf(acc[m][n][0] + bv_); o.y = f2bf(acc[m][n][1] + bv_);
        o.z = f2bf(acc[m][n][2] + bv_); o.w = f2bf(acc[m][n][3] + bv_);
        *reinterpret_cast<ushort4*>(&vt[(size_t)col * Mm + row]) = o;
      } else {
#pragma unroll
        for (int j = 0; j < 4; ++j)
          dstRM[(size_t)(row + j) * Dd + col] = f2bf(acc[m][n][j] + bv_);
      }
    }
  }
}

// Out-projection GEMM: C[m][n] = sum_k A[m][k] * Bt[n][k] + bias[n], f32 out.
__global__ __launch_bounds__(256) void gemm_out(
    const u16* __restrict__ A, const u16* __restrict__ Bt,
    const float* __restrict__ bias, float* __restrict__ C, int M, int N, int K)
{
  constexpr int BK = 64;
  __shared__ u16 As[128 * BK];
  __shared__ u16 Bs[128 * BK];
  const int tid = threadIdx.x;
  const int wave = tid >> 6, lane = tid & 63;
  const int wr = wave >> 1, wc = wave & 1;
  const int lrow = lane & 15, lk = (lane >> 4) * 8;
  const int m0 = blockIdx.y * 128, n0 = blockIdx.x * 128;
  const int srow = lane >> 3, scol = (lane & 7) * 8;

  f32x4 acc[4][4] = {};

  for (int k0 = 0; k0 < K; k0 += BK) {
    __syncthreads();
#pragma unroll
    for (int i = 0; i < 4; ++i) {
      int g = wave * 4 + i;
      int row = g * 8 + srow;
      gload_lds16(A  + (size_t)(m0 + row) * K + k0 + scol, As + g * 512);
      gload_lds16(Bt + (size_t)(n0 + row) * K + k0 + scol, Bs + g * 512);
    }
    __syncthreads();
#pragma unroll
    for (int kk = 0; kk < 2; ++kk) {
      bf16x8 af[4], bfr[4];
#pragma unroll
      for (int m = 0; m < 4; ++m) af[m]  = ld_frag(As + (wr*64 + m*16 + lrow)*BK + kk*32 + lk);
#pragma unroll
      for (int n = 0; n < 4; ++n) bfr[n] = ld_frag(Bs + (wc*64 + n*16 + lrow)*BK + kk*32 + lk);
      __builtin_amdgcn_s_setprio(1);
#pragma unroll
      for (int m = 0; m < 4; ++m)
#pragma unroll
        for (int n = 0; n < 4; ++n)
          acc[m][n] = __builtin_amdgcn_mfma_f32_16x16x32_bf16(af[m], bfr[n], acc[m][n], 0, 0, 0);
      __builtin_amdgcn_s_setprio(0);
    }
  }

#pragma unroll
  for (int m = 0; m < 4; ++m) {
#pragma unroll
    for (int n = 0; n < 4; ++n) {
      int row = m0 + wr*64 + m*16 + (lane >> 4) * 4;
      int col = n0 + wc*64 + n*16 + lrow;
      float bv = bias[col];
#pragma unroll
      for (int j = 0; j < 4; ++j)
        C[(size_t)(row + j) * N + col] = acc[m][n][j] + bv;
    }
  }
}

// Flash attention, swapped-operand, log2-domain, no max tracking, psum via
// ones-MFMA; 8 waves / 128 q-rows per block (R10). THIS ROUND (T4): the
// end-of-iter __syncthreads (which drains vmcnt(0), exposing the just-issued
// prefetch's latency every tile) is replaced by the m201-proven raw-barrier +
// counted-vmcnt schedule:
//   issue stage(t+1) -> buf^1      (buf^1 free: barrier#2 of iter t-1)
//   s_waitcnt vmcnt(2)             (waits only for stage(t), issued a full
//                                   iter ago; the 2 = stage(t+1) stays in flight)
//   s_barrier                      (all waves' tile-t data visible)
//   compute(t) from buf            (unchanged)
//   s_barrier                      (WAR: all waves done reading buf before
//                                   iter t+1 overwrites it)
// vmcnt retires in issue order (m135); gloads are the only VMEM in the loop.
__global__ __launch_bounds__(512) void attn_fwd(
    const u16* __restrict__ Qm, const u16* __restrict__ Km,
    const u16* __restrict__ Vt, u16* __restrict__ Om)
{
  __shared__ u16 Ks[2][4096];      // K tile dbuf; whole 16KB doubles as Q staging
  __shared__ u16 Vs[2][4096];      // V^T tile dbuf: [dh][key], XOR-swizzled

  const int tid = threadIdx.x;
  const int wave = tid >> 6, lane = tid & 63;  // 8 waves
  const int lrow = lane & 15, lk = (lane >> 4) * 8;
  const int swz = (lrow & 7) << 3;            // u16-index XOR for fragment reads
  const int b = blockIdx.x >> 4, h = blockIdx.x & 15;
  const int rb = b * Ls;
  const int cb0 = h * DhC;
  const int q0 = blockIdx.y * 128;
  const int srow = lane >> 3;
  const int scol = ((lane & 7) ^ srow) * 8;   // pre-swizzled source chunk

  // per-tile staging: wave stages chunk `wave` (rows wave*8..+7) of K and V^T
  const u16* kg = Km + (size_t)(rb + wave * 8 + srow) * Dd + cb0 + scol;
  const u16* vg = Vt + (size_t)(cb0 + wave * 8 + srow) * Mm + rb + scol;
  u16* ksflat = &Ks[0][0];
  u16* vsflat = &Vs[0][0];
  u16* ksl = ksflat + wave * 512;
  u16* vsl = vsflat + wave * 512;
  constexpr int LBUF = 4096;                  // u16 distance between dbuf halves

  // prologue: Q (128x64 = 16KB) -> entire Ks dbuf; V0 -> Vs[0]
#pragma unroll
  for (int g = 0; g < 2; ++g)
    gload_lds16(Qm + (size_t)(rb + q0 + wave * 16 + g * 8 + srow) * Dd + cb0 + scol,
                ksflat + (wave * 2 + g) * 512);
  gload_lds16(vg, vsl);
  __syncthreads();

  // Q fragments (16 q-rows per wave), pre-scaled by 0.25*log2(e)
  constexpr float SCL = 0.25f * 1.44269504088896f;
  bf16x8 aq0 = ld_frag(ksflat + (wave * 16 + lrow) * 64 + (lk ^ swz));
  bf16x8 aq1 = ld_frag(ksflat + (wave * 16 + lrow) * 64 + ((32 + lk) ^ swz));
#pragma unroll
  for (int e = 0; e < 8; e += 2) {
    unsigned d0 = cvt_pk_bf16(SCL * bf2f((u16)aq0[e]), SCL * bf2f((u16)aq0[e + 1]));
    unsigned d1 = cvt_pk_bf16(SCL * bf2f((u16)aq1[e]), SCL * bf2f((u16)aq1[e + 1]));
    aq0[e] = (short)(d0 & 0xffff); aq0[e + 1] = (short)(d0 >> 16);
    aq1[e] = (short)(d1 & 0xffff); aq1[e + 1] = (short)(d1 >> 16);
  }
  __syncthreads();       // all waves done reading Q
  gload_lds16(kg, ksl);  // K0 over the Q staging area (Ks[0])
  __syncthreads();       // K0+V0 ready (this barrier drains vmcnt)

  // ones A-fragment for the psum MFMA (bf16 1.0 = 0x3F80)
  bf16x8 ones;
#pragma unroll
  for (int e = 0; e < 8; ++e) ones[e] = (short)0x3F80;

  f32x4 accO[4] = {};
  f32x4 acc_ps = {};   // column sums of P (all 4 elements equal)

  int nb = 0;
  for (int kv0 = 0; kv0 < Ls; kv0 += 64) {
    // issue next tile's stage; counted wait keeps it in flight across compute
    if (kv0 + 64 < Ls) {
      int dst = (nb ^ 1) * LBUF;
      gload_lds16(kg + (size_t)(kv0 + 64) * Dd, ksl + dst);
      gload_lds16(vg + kv0 + 64, vsl + dst);
      asm volatile("s_waitcnt vmcnt(2)" ::: "memory");  // my stage(t) landed
    } else {
      asm volatile("s_waitcnt vmcnt(0)" ::: "memory");  // tail: drain stage(31)
    }
    __builtin_amdgcn_s_barrier();                       // all waves' tile-t in LDS
    const u16* ks = ksflat + nb * LBUF;
    const u16* vs = vsflat + nb * LBUF;

    // S^T (log2 units): s[kb][j] = S[q=lrow][key=16kb+4hi+j]
    f32x4 s[4];
#pragma unroll
    for (int kb = 0; kb < 4; ++kb) {
      const u16* kr = ks + (kb * 16 + lrow) * 64;
      bf16x8 bk0 = ld_frag(kr + (lk ^ swz));
      bf16x8 bk1 = ld_frag(kr + ((32 + lk) ^ swz));
      f32x4 t = {};
      __builtin_amdgcn_s_setprio(1);
      t = __builtin_amdgcn_mfma_f32_16x16x32_bf16(bk0, aq0, t, 0, 0, 0);
      t = __builtin_amdgcn_mfma_f32_16x16x32_bf16(bk1, aq1, t, 0, 0, 0);
      __builtin_amdgcn_s_setprio(0);
      s[kb] = t;
    }

    // p = exp2(s) directly (no max subtraction); pack to bf16 pairs
    unsigned u00 = cvt_pk_bf16(__builtin_amdgcn_exp2f(s[0][0]), __builtin_amdgcn_exp2f(s[0][1]));
    unsigned u01 = cvt_pk_bf16(__builtin_amdgcn_exp2f(s[0][2]), __builtin_amdgcn_exp2f(s[0][3]));
    unsigned u10 = cvt_pk_bf16(__builtin_amdgcn_exp2f(s[1][0]), __builtin_amdgcn_exp2f(s[1][1]));
    unsigned u11 = cvt_pk_bf16(__builtin_amdgcn_exp2f(s[1][2]), __builtin_amdgcn_exp2f(s[1][3]));
    unsigned u20 = cvt_pk_bf16(__builtin_amdgcn_exp2f(s[2][0]), __builtin_amdgcn_exp2f(s[2][1]));
    unsigned u21 = cvt_pk_bf16(__builtin_amdgcn_exp2f(s[2][2]), __builtin_amdgcn_exp2f(s[2][3]));
    unsigned u30 = cvt_pk_bf16(__builtin_amdgcn_exp2f(s[3][0]), __builtin_amdgcn_exp2f(s[3][1]));
    unsigned u31 = cvt_pk_bf16(__builtin_amdgcn_exp2f(s[3][2]), __builtin_amdgcn_exp2f(s[3][3]));

    // in-register redistribution to B-frag layout:
    // {reg kb-bit <-> lane bit5} then {reg pair-bit <-> lane bit4}
    asm("v_permlane32_swap_b32 %0, %1" : "+v"(u00), "+v"(u10));
    asm("v_permlane16_swap_b32 %0, %1" : "+v"(u00), "+v"(u10));
    asm("v_permlane32_swap_b32 %0, %1" : "+v"(u01), "+v"(u11));
    asm("v_permlane16_swap_b32 %0, %1" : "+v"(u01), "+v"(u11));
    asm("v_permlane32_swap_b32 %0, %1" : "+v"(u20), "+v"(u30));
    asm("v_permlane16_swap_b32 %0, %1" : "+v"(u20), "+v"(u30));
    asm("v_permlane32_swap_b32 %0, %1" : "+v"(u21), "+v"(u31));
    asm("v_permlane16_swap_b32 %0, %1" : "+v"(u21), "+v"(u31));

    union { unsigned u[4]; bf16x8 v; } apc0, apc1;
    apc0.u[0] = u00; apc0.u[1] = u01; apc0.u[2] = u10; apc0.u[3] = u11;
    apc1.u[0] = u20; apc1.u[1] = u21; apc1.u[2] = u30; apc1.u[3] = u31;

    // O^T += V^T P^T ; psum += ones . P  (matrix pipe)
#pragma unroll
    for (int kk2 = 0; kk2 < 2; ++kk2) {
      bf16x8 ap = kk2 == 0 ? apc0.v : apc1.v;
      __builtin_amdgcn_s_setprio(1);
#pragma unroll
      for (int cb = 0; cb < 4; ++cb) {
        const u16* vr = vs + (cb * 16 + lrow) * 64;
        bf16x8 bv = ld_frag(vr + ((kk2 * 32 + lk) ^ swz));
        accO[cb] = __builtin_amdgcn_mfma_f32_16x16x32_bf16(bv, ap, accO[cb], 0, 0, 0);
      }
      acc_ps = __builtin_amdgcn_mfma_f32_16x16x32_bf16(ones, ap, acc_ps, 0, 0, 0);
      __builtin_amdgcn_s_setprio(0);
    }

    // WAR barrier: all waves done reading buf nb before t+1 overwrites it
    if (kv0 + 64 < Ls) __builtin_amdgcn_s_barrier();
    nb ^= 1;
  }

  // epilogue: lane holds O[q=lrow][d = cb*16 + 4hi + j]; acc_ps[0] = ssum(q)
  float rinv = 1.0f / acc_ps[0];
  const size_t orow = (size_t)(rb + q0 + wave * 16 + lrow) * Dd + cb0;
#pragma unroll
  for (int cb = 0; cb < 4; ++cb) {
    uint2 o;
    o.x = cvt_pk_bf16(accO[cb][0] * rinv, accO[cb][1] * rinv);
    o.y = cvt_pk_bf16(accO[cb][2] * rinv, accO[cb][3] * rinv);
    *reinterpret_cast<uint2*>(&Om[orow + cb * 16 + (lk >> 1)]) = o;
  }
}

extern "C" void kernel_launch(void* const* d_in, const int* in_sizes, int n_in,
                              void* d_out, int out_size, void* d_ws, size_t ws_size,
                              hipStream_t stream) {
  (void)in_sizes; (void)n_in; (void)out_size; (void)ws_size;
  const float* x  = (const float*)d_in[0];
  const float* wq = (const float*)d_in[1];
  const float* bq = (const float*)d_in[2];
  const float* wk = (const float*)d_in[3];
  const float* bk = (const float*)d_in[4];
  const float* wv = (const float*)d_in[5];
  const float* bv = (const float*)d_in[6];
  const float* wo = (const float*)d_in[7];
  const float* bo = (const float*)d_in[8];
  float* out = (float*)d_out;

  u16* ws  = (u16*)d_ws;
  u16* xb  = ws;                          // 8192x1024 (x bf16; reused as attn out)
  u16* wqb = xb  + (size_t)Mm * Dd;       // 1024x1024 each; wq,wk,wv CONTIGUOUS
  u16* wkb = wqb + (size_t)Dd * Dd;
  u16* wvb = wkb + (size_t)Dd * Dd;
  u16* wob = wvb + (size_t)Dd * Dd;
  u16* qm  = wob + (size_t)Dd * Dd;       // 8192x1024
  u16* km  = qm  + (size_t)Mm * Dd;       // 8192x1024
  u16* vt  = km  + (size_t)Mm * Dd;       // 1024x8192 (V^T)
  u16* om  = xb;                          // alias: xb content dead after QKV GEMM

  cvt_all<<<2048, 256, 0, stream>>>(x, wq, wk, wv, wo, xb, wqb, wkb, wvb, wob);

  dim3 qkvgrid(3 * Dd / 128, Mm / 128);   // 24 x 64
  gemm_qkv<<<qkvgrid, 256, 0, stream>>>(xb, wqb, bq, bk, bv, qm, km, vt);

  dim3 agrid(Bb * Hh, Ls / 128);          // 64 x 16 = 1024 blocks, 4/CU
  attn_fwd<<<agrid, 512, 0, stream>>>(qm, km, vt, om);

  dim3 ogrid(Dd / 128, Mm / 128);
  gemm_out<<<ogrid, 256, 0, stream>>>(om, wob, bo, out, Mm, Dd, Dd);
}

// Round 12
// 197.222 us; speedup vs baseline: 1.0496x; 1.0496x over previous
//
#include <hip/hip_runtime.h>
#include <hip/hip_bf16.h>

#define DEVI __device__ __forceinline__

using u16 = unsigned short;
typedef __attribute__((ext_vector_type(8))) short bf16x8;
typedef __attribute__((ext_vector_type(4))) short bf16x4;
typedef __attribute__((ext_vector_type(4))) float f32x4;

constexpr int Bb = 4, Ls = 2048, Dd = 1024, Hh = 16, DhC = 64;
constexpr int Mm = Bb * Ls; // 8192

DEVI u16 f2bf(float f) {
  union { float f; unsigned u; } x; x.f = f;
  unsigned r = x.u + 0x7FFFu + ((x.u >> 16) & 1u);
  return (u16)(r >> 16);
}
DEVI float bf2f(u16 b) {
  union { unsigned u; float f; } x; x.u = ((unsigned)b) << 16;
  return x.f;
}

// pack two f32 -> two bf16 (RTNE): D[15:0]=bf16(a), D[31:16]=bf16(b)
DEVI unsigned cvt_pk_bf16(float a, float b) {
  unsigned d;
  asm("v_cvt_pk_bf16_f32 %0, %1, %2" : "=v"(d) : "v"(a), "v"(b));
  return d;
}

DEVI void gload_lds16(const u16* g, u16* l) {
  __builtin_amdgcn_global_load_lds(
      (const __attribute__((address_space(1))) unsigned int*)g,
      (__attribute__((address_space(3))) unsigned int*)l, 16, 0, 0);
}

DEVI bf16x8 ld_frag(const u16* p) { return *reinterpret_cast<const bf16x8*>(p); }

// single launch: x (8192x1024) + all four 1024x1024 weights
__global__ void cvt_all(const float* __restrict__ x,
                        const float* __restrict__ wq, const float* __restrict__ wk,
                        const float* __restrict__ wv, const float* __restrict__ wo,
                        u16* __restrict__ xb,
                        u16* __restrict__ wqb, u16* __restrict__ wkb,
                        u16* __restrict__ wvb, u16* __restrict__ wob) {
  const int tid = blockIdx.x * blockDim.x + threadIdx.x;  // grid 2048 x 256
  constexpr int NT = 2048 * 256;
  constexpr int N4X = Mm * Dd / 4;       // 2M float4
  constexpr int N4W = Dd * Dd / 4;       // 256K float4 per weight
  for (int i = tid; i < N4X; i += NT) {
    float4 v = reinterpret_cast<const float4*>(x)[i];
    reinterpret_cast<ushort4*>(xb)[i] =
        make_ushort4(f2bf(v.x), f2bf(v.y), f2bf(v.z), f2bf(v.w));
  }
  for (int i = tid; i < 4 * N4W; i += NT) {
    int which = i / N4W, off = i - which * N4W;
    const float* s = which == 0 ? wq : which == 1 ? wk : which == 2 ? wv : wo;
    u16* d = which == 0 ? wqb : which == 1 ? wkb : which == 2 ? wvb : wob;
    float4 v = reinterpret_cast<const float4*>(s)[off];
    reinterpret_cast<ushort4*>(d)[off] =
        make_ushort4(f2bf(v.x), f2bf(v.y), f2bf(v.z), f2bf(v.w));
  }
}

// Fused QKV projection, m201-style 256x256 8-wave 4-phase lockstep schedule.
// A (8192x1024) @ W^T, W = [wq;wk;wv] (3072x1024 contiguous). q,k row-major;
// v written transposed (vt[dh][m]).
// LDS tiles [256][64] bf16, chunk16-XOR-swizzled (chunk ^= row&7) staged via
// global_load_lds with pre-swizzled SOURCE (rule #21); ds_read applies the
// same XOR -> 2-way bank aliasing only (free).
// Per K-step, 4 phases (serpentine quadrants, min ds_read traffic):
//   P0: LDA fm0-3, LDB fn0-1 | stage q0(t+1) | bar | 16 MFMA acc[0-3][0-1] | bar
//   P1: LDB fn2-3            | stage q1(t+1) | bar | 16 MFMA acc[0-3][2-3] | bar
//   P2: LDA fm4-7            | stage q2(t+1) | bar | 16 MFMA acc[4-7][2-3] | bar
//   P3: (regs live)          | stage q3(t+1) | bar | 16 MFMA acc[4-7][0-1] | vmcnt | bar
// The counted drain at P3 end waits on loads issued >=1 MFMA-phase (~600cyc)
// earlier -> staging latency hidden (T3+T4 mechanism).
__global__ __launch_bounds__(512) void gemm_qkv256(
    const u16* __restrict__ A, const u16* __restrict__ W,
    const float* __restrict__ bq, const float* __restrict__ bk2,
    const float* __restrict__ bv,
    u16* __restrict__ qm, u16* __restrict__ km, u16* __restrict__ vt)
{
  constexpr int K = 1024, BK = 64, NSTEP = K / BK;  // 16
  __shared__ u16 lds[2][2][256 * 64];               // 128 KiB: [buf][A,B]

  const int tid = threadIdx.x;
  const int wave = tid >> 6, lane = tid & 63;
  const int wr = wave >> 2, wc = wave & 3;          // 2M x 4N waves
  const int lrow = lane & 15, hi = lane >> 4, lk = hi * 8;
  const int swz = (lrow & 7) << 3;                  // u16-index XOR for reads
  const int m0 = blockIdx.y * 256;
  const int n0g = blockIdx.x * 256;                 // [0, 3072)

  // staging geometry: chunk c = p*512 + tid ; row = c>>3 (0..255),
  // source k-chunk = (c&7) ^ (row&7) (pre-swizzle), LDS dest linear c*16B
  // (dest = wave-uniform base + lane*16B since c = p*512 + wave*64 + lane).
  const int c_row[4] = { (0*512 + tid) >> 3, (1*512 + tid) >> 3,
                         (2*512 + tid) >> 3, (3*512 + tid) >> 3 };
  int c_kc[4];
#pragma unroll
  for (int p = 0; p < 4; ++p)
    c_kc[p] = (((p * 512 + tid) & 7) ^ (c_row[p] & 7)) * 8;

  f32x4 acc[8][4] = {};

  // prologue: stage tile 0 fully (A + B, 4 quarters each)
#pragma unroll
  for (int p = 0; p < 4; ++p) {
    int c = p * 512 + tid;
    gload_lds16(A + (size_t)(m0 + c_row[p]) * K + c_kc[p], &lds[0][0][0] + c * 8);
    gload_lds16(W + (size_t)(n0g + c_row[p]) * K + c_kc[p], &lds[0][1][0] + c * 8);
  }
  __syncthreads();

  for (int t = 0; t < NSTEP; ++t) {
    const u16* Ab = &lds[t & 1][0][0];
    const u16* Bb = &lds[t & 1][1][0];
    u16* An = &lds[(t + 1) & 1][0][0];
    u16* Bn = &lds[(t + 1) & 1][1][0];
    const int k1 = (t + 1) * BK;
    const bool more = (t + 1 < NSTEP);

    bf16x8 a[4][2], b0[2][2], b1[2][2];

#define STAGE_Q(p)                                                             \
    if (more) {                                                                \
      int c = (p) * 512 + tid;                                                 \
      gload_lds16(A + (size_t)(m0 + c_row[p]) * K + k1 + c_kc[p], An + c * 8); \
      gload_lds16(W + (size_t)(n0g + c_row[p]) * K + k1 + c_kc[p], Bn + c * 8);\
    }

    // ---- phase 0
#pragma unroll
    for (int f = 0; f < 4; ++f) {
      int row = wr * 128 + f * 16 + lrow;
      a[f][0] = ld_frag(Ab + row * 64 + (lk ^ swz));
      a[f][1] = ld_frag(Ab + row * 64 + ((32 + lk) ^ swz));
    }
#pragma unroll
    for (int f = 0; f < 2; ++f) {
      int row = wc * 64 + f * 16 + lrow;
      b0[f][0] = ld_frag(Bb + row * 64 + (lk ^ swz));
      b0[f][1] = ld_frag(Bb + row * 64 + ((32 + lk) ^ swz));
    }
    STAGE_Q(0);
    __builtin_amdgcn_s_barrier();
    __builtin_amdgcn_s_setprio(1);
#pragma unroll
    for (int fm = 0; fm < 4; ++fm)
#pragma unroll
      for (int fn = 0; fn < 2; ++fn)
#pragma unroll
        for (int kk = 0; kk < 2; ++kk)
          acc[fm][fn] = __builtin_amdgcn_mfma_f32_16x16x32_bf16(a[fm][kk], b0[fn][kk], acc[fm][fn], 0, 0, 0);
    __builtin_amdgcn_s_setprio(0);
    __builtin_amdgcn_s_barrier();

    // ---- phase 1
#pragma unroll
    for (int f = 0; f < 2; ++f) {
      int row = wc * 64 + (2 + f) * 16 + lrow;
      b1[f][0] = ld_frag(Bb + row * 64 + (lk ^ swz));
      b1[f][1] = ld_frag(Bb + row * 64 + ((32 + lk) ^ swz));
    }
    STAGE_Q(1);
    __builtin_amdgcn_s_barrier();
    __builtin_amdgcn_s_setprio(1);
#pragma unroll
    for (int fm = 0; fm < 4; ++fm)
#pragma unroll
      for (int fn = 0; fn < 2; ++fn)
#pragma unroll
        for (int kk = 0; kk < 2; ++kk)
          acc[fm][2 + fn] = __builtin_amdgcn_mfma_f32_16x16x32_bf16(a[fm][kk], b1[fn][kk], acc[fm][2 + fn], 0, 0, 0);
    __builtin_amdgcn_s_setprio(0);
    __builtin_amdgcn_s_barrier();

    // ---- phase 2
#pragma unroll
    for (int f = 0; f < 4; ++f) {
      int row = wr * 128 + (4 + f) * 16 + lrow;
      a[f][0] = ld_frag(Ab + row * 64 + (lk ^ swz));
      a[f][1] = ld_frag(Ab + row * 64 + ((32 + lk) ^ swz));
    }
    STAGE_Q(2);
    __builtin_amdgcn_s_barrier();
    __builtin_amdgcn_s_setprio(1);
#pragma unroll
    for (int fm = 0; fm < 4; ++fm)
#pragma unroll
      for (int fn = 0; fn < 2; ++fn)
#pragma unroll
        for (int kk = 0; kk < 2; ++kk)
          acc[4 + fm][2 + fn] = __builtin_amdgcn_mfma_f32_16x16x32_bf16(a[fm][kk], b1[fn][kk], acc[4 + fm][2 + fn], 0, 0, 0);
    __builtin_amdgcn_s_setprio(0);
    __builtin_amdgcn_s_barrier();

    // ---- phase 3 (a = fm4-7, b0 still live)
    STAGE_Q(3);
    __builtin_amdgcn_s_barrier();
    __builtin_amdgcn_s_setprio(1);
#pragma unroll
    for (int fm = 0; fm < 4; ++fm)
#pragma unroll
      for (int fn = 0; fn < 2; ++fn)
#pragma unroll
        for (int kk = 0; kk < 2; ++kk)
          acc[4 + fm][fn] = __builtin_amdgcn_mfma_f32_16x16x32_bf16(a[fm][kk], b0[fn][kk], acc[4 + fm][fn], 0, 0, 0);
    __builtin_amdgcn_s_setprio(0);
    if (more) asm volatile("s_waitcnt vmcnt(0)" ::: "memory");  // tile t+1 landed
    __builtin_amdgcn_s_barrier();
#undef STAGE_Q
  }

  // epilogue
  const int region = blockIdx.x >> 2;         // 0=q, 1=k, 2=v
  const int nc0 = (blockIdx.x & 3) * 256;     // n within the 1024 region
  const float* bias = region == 0 ? bq : region == 1 ? bk2 : bv;
  u16* dstRM = region == 0 ? qm : km;

#pragma unroll
  for (int fm = 0; fm < 8; ++fm) {
#pragma unroll
    for (int fn = 0; fn < 4; ++fn) {
      int row = m0 + wr * 128 + fm * 16 + hi * 4;
      int col = nc0 + wc * 64 + fn * 16 + lrow;
      float bv_ = bias[col];
      if (region == 2) {
        ushort4 o;
        o.x = f2bf(acc[fm][fn][0] + bv_); o.y = f2bf(acc[fm][fn][1] + bv_);
        o.z = f2bf(acc[fm][fn][2] + bv_); o.w = f2bf(acc[fm][fn][3] + bv_);
        *reinterpret_cast<ushort4*>(&vt[(size_t)col * Mm + row]) = o;
      } else {
#pragma unroll
        for (int j = 0; j < 4; ++j)
          dstRM[(size_t)(row + j) * Dd + col] = f2bf(acc[fm][fn][j] + bv_);
      }
    }
  }
}

// Out-projection GEMM: C[m][n] = sum_k A[m][k] * Bt[n][k] + bias[n], f32 out.
__global__ __launch_bounds__(256) void gemm_out(
    const u16* __restrict__ A, const u16* __restrict__ Bt,
    const float* __restrict__ bias, float* __restrict__ C, int M, int N, int K)
{
  constexpr int BK = 64;
  __shared__ u16 As[128 * BK];
  __shared__ u16 Bs[128 * BK];
  const int tid = threadIdx.x;
  const int wave = tid >> 6, lane = tid & 63;
  const int wr = wave >> 1, wc = wave & 1;
  const int lrow = lane & 15, lk = (lane >> 4) * 8;
  const int m0 = blockIdx.y * 128, n0 = blockIdx.x * 128;
  const int srow = lane >> 3, scol = (lane & 7) * 8;

  f32x4 acc[4][4] = {};

  for (int k0 = 0; k0 < K; k0 += BK) {
    __syncthreads();
#pragma unroll
    for (int i = 0; i < 4; ++i) {
      int g = wave * 4 + i;
      int row = g * 8 + srow;
      gload_lds16(A  + (size_t)(m0 + row) * K + k0 + scol, As + g * 512);
      gload_lds16(Bt + (size_t)(n0 + row) * K + k0 + scol, Bs + g * 512);
    }
    __syncthreads();
#pragma unroll
    for (int kk = 0; kk < 2; ++kk) {
      bf16x8 af[4], bfr[4];
#pragma unroll
      for (int m = 0; m < 4; ++m) af[m]  = ld_frag(As + (wr*64 + m*16 + lrow)*BK + kk*32 + lk);
#pragma unroll
      for (int n = 0; n < 4; ++n) bfr[n] = ld_frag(Bs + (wc*64 + n*16 + lrow)*BK + kk*32 + lk);
      __builtin_amdgcn_s_setprio(1);
#pragma unroll
      for (int m = 0; m < 4; ++m)
#pragma unroll
        for (int n = 0; n < 4; ++n)
          acc[m][n] = __builtin_amdgcn_mfma_f32_16x16x32_bf16(af[m], bfr[n], acc[m][n], 0, 0, 0);
      __builtin_amdgcn_s_setprio(0);
    }
  }

#pragma unroll
  for (int m = 0; m < 4; ++m) {
#pragma unroll
    for (int n = 0; n < 4; ++n) {
      int row = m0 + wr*64 + m*16 + (lane >> 4) * 4;
      int col = n0 + wc*64 + n*16 + lrow;
      float bv = bias[col];
#pragma unroll
      for (int j = 0; j < 4; ++j)
        C[(size_t)(row + j) * N + col] = acc[m][n][j] + bv;
    }
  }
}

// Flash attention, swapped-operand, log2-domain, no max tracking, psum via
// ones-MFMA; 8 waves / 128 q-rows per block; counted-vmcnt loop (R11).
__global__ __launch_bounds__(512) void attn_fwd(
    const u16* __restrict__ Qm, const u16* __restrict__ Km,
    const u16* __restrict__ Vt, u16* __restrict__ Om)
{
  __shared__ u16 Ks[2][4096];      // K tile dbuf; whole 16KB doubles as Q staging
  __shared__ u16 Vs[2][4096];      // V^T tile dbuf: [dh][key], XOR-swizzled

  const int tid = threadIdx.x;
  const int wave = tid >> 6, lane = tid & 63;  // 8 waves
  const int lrow = lane & 15, lk = (lane >> 4) * 8;
  const int swz = (lrow & 7) << 3;            // u16-index XOR for fragment reads
  const int b = blockIdx.x >> 4, h = blockIdx.x & 15;
  const int rb = b * Ls;
  const int cb0 = h * DhC;
  const int q0 = blockIdx.y * 128;
  const int srow = lane >> 3;
  const int scol = ((lane & 7) ^ srow) * 8;   // pre-swizzled source chunk

  const u16* kg = Km + (size_t)(rb + wave * 8 + srow) * Dd + cb0 + scol;
  const u16* vg = Vt + (size_t)(cb0 + wave * 8 + srow) * Mm + rb + scol;
  u16* ksflat = &Ks[0][0];
  u16* vsflat = &Vs[0][0];
  u16* ksl = ksflat + wave * 512;
  u16* vsl = vsflat + wave * 512;
  constexpr int LBUF = 4096;

  // prologue: Q (128x64 = 16KB) -> entire Ks dbuf; V0 -> Vs[0]
#pragma unroll
  for (int g = 0; g < 2; ++g)
    gload_lds16(Qm + (size_t)(rb + q0 + wave * 16 + g * 8 + srow) * Dd + cb0 + scol,
                ksflat + (wave * 2 + g) * 512);
  gload_lds16(vg, vsl);
  __syncthreads();

  constexpr float SCL = 0.25f * 1.44269504088896f;
  bf16x8 aq0 = ld_frag(ksflat + (wave * 16 + lrow) * 64 + (lk ^ swz));
  bf16x8 aq1 = ld_frag(ksflat + (wave * 16 + lrow) * 64 + ((32 + lk) ^ swz));
#pragma unroll
  for (int e = 0; e < 8; e += 2) {
    unsigned d0 = cvt_pk_bf16(SCL * bf2f((u16)aq0[e]), SCL * bf2f((u16)aq0[e + 1]));
    unsigned d1 = cvt_pk_bf16(SCL * bf2f((u16)aq1[e]), SCL * bf2f((u16)aq1[e + 1]));
    aq0[e] = (short)(d0 & 0xffff); aq0[e + 1] = (short)(d0 >> 16);
    aq1[e] = (short)(d1 & 0xffff); aq1[e + 1] = (short)(d1 >> 16);
  }
  __syncthreads();       // all waves done reading Q
  gload_lds16(kg, ksl);  // K0 over the Q staging area (Ks[0])
  __syncthreads();       // K0+V0 ready

  bf16x8 ones;
#pragma unroll
  for (int e = 0; e < 8; ++e) ones[e] = (short)0x3F80;

  f32x4 accO[4] = {};
  f32x4 acc_ps = {};

  int nb = 0;
  for (int kv0 = 0; kv0 < Ls; kv0 += 64) {
    if (kv0 + 64 < Ls) {
      int dst = (nb ^ 1) * LBUF;
      gload_lds16(kg + (size_t)(kv0 + 64) * Dd, ksl + dst);
      gload_lds16(vg + kv0 + 64, vsl + dst);
      asm volatile("s_waitcnt vmcnt(2)" ::: "memory");
    } else {
      asm volatile("s_waitcnt vmcnt(0)" ::: "memory");
    }
    __builtin_amdgcn_s_barrier();
    const u16* ks = ksflat + nb * LBUF;
    const u16* vs = vsflat + nb * LBUF;

    f32x4 s[4];
#pragma unroll
    for (int kb = 0; kb < 4; ++kb) {
      const u16* kr = ks + (kb * 16 + lrow) * 64;
      bf16x8 bk0 = ld_frag(kr + (lk ^ swz));
      bf16x8 bk1 = ld_frag(kr + ((32 + lk) ^ swz));
      f32x4 t = {};
      __builtin_amdgcn_s_setprio(1);
      t = __builtin_amdgcn_mfma_f32_16x16x32_bf16(bk0, aq0, t, 0, 0, 0);
      t = __builtin_amdgcn_mfma_f32_16x16x32_bf16(bk1, aq1, t, 0, 0, 0);
      __builtin_amdgcn_s_setprio(0);
      s[kb] = t;
    }

    unsigned u00 = cvt_pk_bf16(__builtin_amdgcn_exp2f(s[0][0]), __builtin_amdgcn_exp2f(s[0][1]));
    unsigned u01 = cvt_pk_bf16(__builtin_amdgcn_exp2f(s[0][2]), __builtin_amdgcn_exp2f(s[0][3]));
    unsigned u10 = cvt_pk_bf16(__builtin_amdgcn_exp2f(s[1][0]), __builtin_amdgcn_exp2f(s[1][1]));
    unsigned u11 = cvt_pk_bf16(__builtin_amdgcn_exp2f(s[1][2]), __builtin_amdgcn_exp2f(s[1][3]));
    unsigned u20 = cvt_pk_bf16(__builtin_amdgcn_exp2f(s[2][0]), __builtin_amdgcn_exp2f(s[2][1]));
    unsigned u21 = cvt_pk_bf16(__builtin_amdgcn_exp2f(s[2][2]), __builtin_amdgcn_exp2f(s[2][3]));
    unsigned u30 = cvt_pk_bf16(__builtin_amdgcn_exp2f(s[3][0]), __builtin_amdgcn_exp2f(s[3][1]));
    unsigned u31 = cvt_pk_bf16(__builtin_amdgcn_exp2f(s[3][2]), __builtin_amdgcn_exp2f(s[3][3]));

    asm("v_permlane32_swap_b32 %0, %1" : "+v"(u00), "+v"(u10));
    asm("v_permlane16_swap_b32 %0, %1" : "+v"(u00), "+v"(u10));
    asm("v_permlane32_swap_b32 %0, %1" : "+v"(u01), "+v"(u11));
    asm("v_permlane16_swap_b32 %0, %1" : "+v"(u01), "+v"(u11));
    asm("v_permlane32_swap_b32 %0, %1" : "+v"(u20), "+v"(u30));
    asm("v_permlane16_swap_b32 %0, %1" : "+v"(u20), "+v"(u30));
    asm("v_permlane32_swap_b32 %0, %1" : "+v"(u21), "+v"(u31));
    asm("v_permlane16_swap_b32 %0, %1" : "+v"(u21), "+v"(u31));

    union { unsigned u[4]; bf16x8 v; } apc0, apc1;
    apc0.u[0] = u00; apc0.u[1] = u01; apc0.u[2] = u10; apc0.u[3] = u11;
    apc1.u[0] = u20; apc1.u[1] = u21; apc1.u[2] = u30; apc1.u[3] = u31;

#pragma unroll
    for (int kk2 = 0; kk2 < 2; ++kk2) {
      bf16x8 ap = kk2 == 0 ? apc0.v : apc1.v;
      __builtin_amdgcn_s_setprio(1);
#pragma unroll
      for (int cb = 0; cb < 4; ++cb) {
        const u16* vr = vs + (cb * 16 + lrow) * 64;
        bf16x8 bv = ld_frag(vr + ((kk2 * 32 + lk) ^ swz));
        accO[cb] = __builtin_amdgcn_mfma_f32_16x16x32_bf16(bv, ap, accO[cb], 0, 0, 0);
      }
      acc_ps = __builtin_amdgcn_mfma_f32_16x16x32_bf16(ones, ap, acc_ps, 0, 0, 0);
      __builtin_amdgcn_s_setprio(0);
    }

    if (kv0 + 64 < Ls) __builtin_amdgcn_s_barrier();
    nb ^= 1;
  }

  float rinv = 1.0f / acc_ps[0];
  const size_t orow = (size_t)(rb + q0 + wave * 16 + lrow) * Dd + cb0;
#pragma unroll
  for (int cb = 0; cb < 4; ++cb) {
    uint2 o;
    o.x = cvt_pk_bf16(accO[cb][0] * rinv, accO[cb][1] * rinv);
    o.y = cvt_pk_bf16(accO[cb][2] * rinv, accO[cb][3] * rinv);
    *reinterpret_cast<uint2*>(&Om[orow + cb * 16 + (lk >> 1)]) = o;
  }
}

extern "C" void kernel_launch(void* const* d_in, const int* in_sizes, int n_in,
                              void* d_out, int out_size, void* d_ws, size_t ws_size,
                              hipStream_t stream) {
  (void)in_sizes; (void)n_in; (void)out_size; (void)ws_size;
  const float* x  = (const float*)d_in[0];
  const float* wq = (const float*)d_in[1];
  const float* bq = (const float*)d_in[2];
  const float* wk = (const float*)d_in[3];
  const float* bk = (const float*)d_in[4];
  const float* wv = (const float*)d_in[5];
  const float* bv = (const float*)d_in[6];
  const float* wo = (const float*)d_in[7];
  const float* bo = (const float*)d_in[8];
  float* out = (float*)d_out;

  u16* ws  = (u16*)d_ws;
  u16* xb  = ws;                          // 8192x1024 (x bf16; reused as attn out)
  u16* wqb = xb  + (size_t)Mm * Dd;       // 1024x1024 each; wq,wk,wv CONTIGUOUS
  u16* wkb = wqb + (size_t)Dd * Dd;
  u16* wvb = wkb + (size_t)Dd * Dd;
  u16* wob = wvb + (size_t)Dd * Dd;
  u16* qm  = wob + (size_t)Dd * Dd;       // 8192x1024
  u16* km  = qm  + (size_t)Mm * Dd;       // 8192x1024
  u16* vt  = km  + (size_t)Mm * Dd;       // 1024x8192 (V^T)
  u16* om  = xb;                          // alias: xb content dead after QKV GEMM

  cvt_all<<<2048, 256, 0, stream>>>(x, wq, wk, wv, wo, xb, wqb, wkb, wvb, wob);

  dim3 qkvgrid(3 * Dd / 256, Mm / 256);   // 12 x 32 = 384 blocks
  gemm_qkv256<<<qkvgrid, 512, 0, stream>>>(xb, wqb, bq, bk, bv, qm, km, vt);

  dim3 agrid(Bb * Hh, Ls / 128);          // 64 x 16 = 1024 blocks, 4/CU
  attn_fwd<<<agrid, 512, 0, stream>>>(qm, km, vt, om);

  dim3 ogrid(Dd / 128, Mm / 128);
  gemm_out<<<ogrid, 256, 0, stream>>>(om, wob, bo, out, Mm, Dd, Dd);
}

// Round 13
// 193.959 us; speedup vs baseline: 1.0673x; 1.0168x over previous
//
#include <hip/hip_runtime.h>
#include <hip/hip_bf16.h>

#define DEVI __device__ __forceinline__

using u16 = unsigned short;
typedef __attribute__((ext_vector_type(8))) short bf16x8;
typedef __attribute__((ext_vector_type(4))) short bf16x4;
typedef __attribute__((ext_vector_type(4))) float f32x4;

constexpr int Bb = 4, Ls = 2048, Dd = 1024, Hh = 16, DhC = 64;
constexpr int Mm = Bb * Ls; // 8192

DEVI u16 f2bf(float f) {
  union { float f; unsigned u; } x; x.f = f;
  unsigned r = x.u + 0x7FFFu + ((x.u >> 16) & 1u);
  return (u16)(r >> 16);
}
DEVI float bf2f(u16 b) {
  union { unsigned u; float f; } x; x.u = ((unsigned)b) << 16;
  return x.f;
}

// pack two f32 -> two bf16 (RTNE): D[15:0]=bf16(a), D[31:16]=bf16(b)
DEVI unsigned cvt_pk_bf16(float a, float b) {
  unsigned d;
  asm("v_cvt_pk_bf16_f32 %0, %1, %2" : "=v"(d) : "v"(a), "v"(b));
  return d;
}

DEVI void gload_lds16(const u16* g, u16* l) {
  __builtin_amdgcn_global_load_lds(
      (const __attribute__((address_space(1))) unsigned int*)g,
      (__attribute__((address_space(3))) unsigned int*)l, 16, 0, 0);
}

DEVI bf16x8 ld_frag(const u16* p) { return *reinterpret_cast<const bf16x8*>(p); }

// single launch: x (8192x1024) + all four 1024x1024 weights
__global__ void cvt_all(const float* __restrict__ x,
                        const float* __restrict__ wq, const float* __restrict__ wk,
                        const float* __restrict__ wv, const float* __restrict__ wo,
                        u16* __restrict__ xb,
                        u16* __restrict__ wqb, u16* __restrict__ wkb,
                        u16* __restrict__ wvb, u16* __restrict__ wob) {
  const int tid = blockIdx.x * blockDim.x + threadIdx.x;  // grid 2048 x 256
  constexpr int NT = 2048 * 256;
  constexpr int N4X = Mm * Dd / 4;       // 2M float4
  constexpr int N4W = Dd * Dd / 4;       // 256K float4 per weight
  for (int i = tid; i < N4X; i += NT) {
    float4 v = reinterpret_cast<const float4*>(x)[i];
    reinterpret_cast<ushort4*>(xb)[i] =
        make_ushort4(f2bf(v.x), f2bf(v.y), f2bf(v.z), f2bf(v.w));
  }
  for (int i = tid; i < 4 * N4W; i += NT) {
    int which = i / N4W, off = i - which * N4W;
    const float* s = which == 0 ? wq : which == 1 ? wk : which == 2 ? wv : wo;
    u16* d = which == 0 ? wqb : which == 1 ? wkb : which == 2 ? wvb : wob;
    float4 v = reinterpret_cast<const float4*>(s)[off];
    reinterpret_cast<ushort4*>(d)[off] =
        make_ushort4(f2bf(v.x), f2bf(v.y), f2bf(v.z), f2bf(v.w));
  }
}

// Fused QKV projection, zero-tail retile of the R12 4-phase schedule:
// 128x256 tile, 8 waves (2M x 4N, each wave 64x64 / acc[4][4]), BK=64,
// 96 KiB LDS (1 block/CU), grid 12x64 = 768 blocks = EXACTLY 3 occupancy
// rounds (R12's 256^2 had 384 blocks -> 1.5 rounds, 25% idle).
// K-step = 2 phases x 16 MFMA; per phase: ds_read subtile | stage 3 quarters
// of tile t+1 | bar | MFMA | bar; counted drain only at K-step end (T3+T4).
// XOR swizzle identical to R12 (chunk16 ^= row&7, pre-swizzled global src).
// T1 XCD-chunked bijective block swizzle (768%8==0): each XCD gets 8
// consecutive row-panels x all 12 col-blocks -> A-panels L2-resident.
__global__ __launch_bounds__(512) void gemm_qkv(
    const u16* __restrict__ A, const u16* __restrict__ W,
    const float* __restrict__ bq, const float* __restrict__ bk2,
    const float* __restrict__ bv,
    u16* __restrict__ qm, u16* __restrict__ km, u16* __restrict__ vt)
{
  constexpr int K = 1024, BK = 64, NSTEP = K / BK;  // 16
  __shared__ u16 ldsA[2][128 * 64];                 // 32 KiB
  __shared__ u16 ldsB[2][256 * 64];                 // 64 KiB

  const int tid = threadIdx.x;
  const int wave = tid >> 6, lane = tid & 63;
  const int wr = wave >> 2, wc = wave & 3;          // 2M x 4N waves
  const int lrow = lane & 15, hi = lane >> 4, lk = hi * 8;
  const int swz = (lrow & 7) << 3;                  // u16-index XOR for reads

  // T1: lin (x-fastest dispatch) -> XCD-chunked remap
  const int lin = blockIdx.y * 12 + blockIdx.x;     // 0..767
  const int nid = (lin & 7) * 96 + (lin >> 3);      // bijective (768/8=96)
  const int bx = nid % 12, by = nid / 12;
  const int m0 = by * 128;
  const int n0g = bx * 256;                         // [0, 3072)

  // staging: chunk c (16B): row = c>>3, src k-chunk = (c&7)^(row&7)
  // A: 1024 chunks (g=0,1); B: 2048 chunks (g=0..3); dest linear c*16B.
  int a_row[2], a_kc[2], b_row[4], b_kc[4];
#pragma unroll
  for (int g = 0; g < 2; ++g) {
    int c = g * 512 + tid;
    a_row[g] = c >> 3;
    a_kc[g] = ((c & 7) ^ (a_row[g] & 7)) * 8;
  }
#pragma unroll
  for (int g = 0; g < 4; ++g) {
    int c = g * 512 + tid;
    b_row[g] = c >> 3;
    b_kc[g] = ((c & 7) ^ (b_row[g] & 7)) * 8;
  }

  f32x4 acc[4][4] = {};

  // prologue: stage tile 0 fully
#pragma unroll
  for (int g = 0; g < 2; ++g)
    gload_lds16(A + (size_t)(m0 + a_row[g]) * K + a_kc[g], &ldsA[0][0] + (g * 512 + tid) * 8);
#pragma unroll
  for (int g = 0; g < 4; ++g)
    gload_lds16(W + (size_t)(n0g + b_row[g]) * K + b_kc[g], &ldsB[0][0] + (g * 512 + tid) * 8);
  __syncthreads();

  for (int t = 0; t < NSTEP; ++t) {
    const u16* Ab = &ldsA[t & 1][0];
    const u16* Bb = &ldsB[t & 1][0];
    u16* An = &ldsA[(t + 1) & 1][0];
    u16* Bn = &ldsB[(t + 1) & 1][0];
    const int k1 = (t + 1) * BK;
    const bool more = (t + 1 < NSTEP);

    bf16x8 a[4][2], b0[2][2], b1[2][2];

    // ---- phase 0: read A(fm0-3) + B(fn0-1); stage A g0,g1 + B g0
#pragma unroll
    for (int f = 0; f < 4; ++f) {
      int row = wr * 64 + f * 16 + lrow;
      a[f][0] = ld_frag(Ab + row * 64 + (lk ^ swz));
      a[f][1] = ld_frag(Ab + row * 64 + ((32 + lk) ^ swz));
    }
#pragma unroll
    for (int f = 0; f < 2; ++f) {
      int row = wc * 64 + f * 16 + lrow;
      b0[f][0] = ld_frag(Bb + row * 64 + (lk ^ swz));
      b0[f][1] = ld_frag(Bb + row * 64 + ((32 + lk) ^ swz));
    }
    if (more) {
      gload_lds16(A + (size_t)(m0 + a_row[0]) * K + k1 + a_kc[0], An + (0 * 512 + tid) * 8);
      gload_lds16(A + (size_t)(m0 + a_row[1]) * K + k1 + a_kc[1], An + (1 * 512 + tid) * 8);
      gload_lds16(W + (size_t)(n0g + b_row[0]) * K + k1 + b_kc[0], Bn + (0 * 512 + tid) * 8);
    }
    __builtin_amdgcn_s_barrier();
    __builtin_amdgcn_s_setprio(1);
#pragma unroll
    for (int fm = 0; fm < 4; ++fm)
#pragma unroll
      for (int fn = 0; fn < 2; ++fn)
#pragma unroll
        for (int kk = 0; kk < 2; ++kk)
          acc[fm][fn] = __builtin_amdgcn_mfma_f32_16x16x32_bf16(a[fm][kk], b0[fn][kk], acc[fm][fn], 0, 0, 0);
    __builtin_amdgcn_s_setprio(0);
    __builtin_amdgcn_s_barrier();

    // ---- phase 1: read B(fn2-3); stage B g1,g2,g3
#pragma unroll
    for (int f = 0; f < 2; ++f) {
      int row = wc * 64 + (2 + f) * 16 + lrow;
      b1[f][0] = ld_frag(Bb + row * 64 + (lk ^ swz));
      b1[f][1] = ld_frag(Bb + row * 64 + ((32 + lk) ^ swz));
    }
    if (more) {
      gload_lds16(W + (size_t)(n0g + b_row[1]) * K + k1 + b_kc[1], Bn + (1 * 512 + tid) * 8);
      gload_lds16(W + (size_t)(n0g + b_row[2]) * K + k1 + b_kc[2], Bn + (2 * 512 + tid) * 8);
      gload_lds16(W + (size_t)(n0g + b_row[3]) * K + k1 + b_kc[3], Bn + (3 * 512 + tid) * 8);
    }
    __builtin_amdgcn_s_barrier();
    __builtin_amdgcn_s_setprio(1);
#pragma unroll
    for (int fm = 0; fm < 4; ++fm)
#pragma unroll
      for (int fn = 0; fn < 2; ++fn)
#pragma unroll
        for (int kk = 0; kk < 2; ++kk)
          acc[fm][2 + fn] = __builtin_amdgcn_mfma_f32_16x16x32_bf16(a[fm][kk], b1[fn][kk], acc[fm][2 + fn], 0, 0, 0);
    __builtin_amdgcn_s_setprio(0);
    if (more) asm volatile("s_waitcnt vmcnt(0)" ::: "memory");  // tile t+1 landed
    __builtin_amdgcn_s_barrier();
  }

  // epilogue
  const int region = bx >> 2;               // 0=q, 1=k, 2=v
  const int nc0 = (bx & 3) * 256;           // n within the 1024 region
  const float* bias = region == 0 ? bq : region == 1 ? bk2 : bv;
  u16* dstRM = region == 0 ? qm : km;

#pragma unroll
  for (int fm = 0; fm < 4; ++fm) {
#pragma unroll
    for (int fn = 0; fn < 4; ++fn) {
      int row = m0 + wr * 64 + fm * 16 + hi * 4;
      int col = nc0 + wc * 64 + fn * 16 + lrow;
      float bv_ = bias[col];
      if (region == 2) {
        ushort4 o;
        o.x = f2bf(acc[fm][fn][0] + bv_); o.y = f2bf(acc[fm][fn][1] + bv_);
        o.z = f2bf(acc[fm][fn][2] + bv_); o.w = f2bf(acc[fm][fn][3] + bv_);
        *reinterpret_cast<ushort4*>(&vt[(size_t)col * Mm + row]) = o;
      } else {
#pragma unroll
        for (int j = 0; j < 4; ++j)
          dstRM[(size_t)(row + j) * Dd + col] = f2bf(acc[fm][fn][j] + bv_);
      }
    }
  }
}

// Out-projection GEMM: C[m][n] = sum_k A[m][k] * Bt[n][k] + bias[n], f32 out.
__global__ __launch_bounds__(256) void gemm_out(
    const u16* __restrict__ A, const u16* __restrict__ Bt,
    const float* __restrict__ bias, float* __restrict__ C, int M, int N, int K)
{
  constexpr int BK = 64;
  __shared__ u16 As[128 * BK];
  __shared__ u16 Bs[128 * BK];
  const int tid = threadIdx.x;
  const int wave = tid >> 6, lane = tid & 63;
  const int wr = wave >> 1, wc = wave & 1;
  const int lrow = lane & 15, lk = (lane >> 4) * 8;
  const int m0 = blockIdx.y * 128, n0 = blockIdx.x * 128;
  const int srow = lane >> 3, scol = (lane & 7) * 8;

  f32x4 acc[4][4] = {};

  for (int k0 = 0; k0 < K; k0 += BK) {
    __syncthreads();
#pragma unroll
    for (int i = 0; i < 4; ++i) {
      int g = wave * 4 + i;
      int row = g * 8 + srow;
      gload_lds16(A  + (size_t)(m0 + row) * K + k0 + scol, As + g * 512);
      gload_lds16(Bt + (size_t)(n0 + row) * K + k0 + scol, Bs + g * 512);
    }
    __syncthreads();
#pragma unroll
    for (int kk = 0; kk < 2; ++kk) {
      bf16x8 af[4], bfr[4];
#pragma unroll
      for (int m = 0; m < 4; ++m) af[m]  = ld_frag(As + (wr*64 + m*16 + lrow)*BK + kk*32 + lk);
#pragma unroll
      for (int n = 0; n < 4; ++n) bfr[n] = ld_frag(Bs + (wc*64 + n*16 + lrow)*BK + kk*32 + lk);
      __builtin_amdgcn_s_setprio(1);
#pragma unroll
      for (int m = 0; m < 4; ++m)
#pragma unroll
        for (int n = 0; n < 4; ++n)
          acc[m][n] = __builtin_amdgcn_mfma_f32_16x16x32_bf16(af[m], bfr[n], acc[m][n], 0, 0, 0);
      __builtin_amdgcn_s_setprio(0);
    }
  }

#pragma unroll
  for (int m = 0; m < 4; ++m) {
#pragma unroll
    for (int n = 0; n < 4; ++n) {
      int row = m0 + wr*64 + m*16 + (lane >> 4) * 4;
      int col = n0 + wc*64 + n*16 + lrow;
      float bv = bias[col];
#pragma unroll
      for (int j = 0; j < 4; ++j)
        C[(size_t)(row + j) * N + col] = acc[m][n][j] + bv;
    }
  }
}

// Flash attention, swapped-operand, log2-domain, no max tracking, psum via
// ones-MFMA; 8 waves / 128 q-rows per block; counted-vmcnt loop (R11).
__global__ __launch_bounds__(512) void attn_fwd(
    const u16* __restrict__ Qm, const u16* __restrict__ Km,
    const u16* __restrict__ Vt, u16* __restrict__ Om)
{
  __shared__ u16 Ks[2][4096];      // K tile dbuf; whole 16KB doubles as Q staging
  __shared__ u16 Vs[2][4096];      // V^T tile dbuf: [dh][key], XOR-swizzled

  const int tid = threadIdx.x;
  const int wave = tid >> 6, lane = tid & 63;  // 8 waves
  const int lrow = lane & 15, lk = (lane >> 4) * 8;
  const int swz = (lrow & 7) << 3;            // u16-index XOR for fragment reads
  const int b = blockIdx.x >> 4, h = blockIdx.x & 15;
  const int rb = b * Ls;
  const int cb0 = h * DhC;
  const int q0 = blockIdx.y * 128;
  const int srow = lane >> 3;
  const int scol = ((lane & 7) ^ srow) * 8;   // pre-swizzled source chunk

  const u16* kg = Km + (size_t)(rb + wave * 8 + srow) * Dd + cb0 + scol;
  const u16* vg = Vt + (size_t)(cb0 + wave * 8 + srow) * Mm + rb + scol;
  u16* ksflat = &Ks[0][0];
  u16* vsflat = &Vs[0][0];
  u16* ksl = ksflat + wave * 512;
  u16* vsl = vsflat + wave * 512;
  constexpr int LBUF = 4096;

  // prologue: Q (128x64 = 16KB) -> entire Ks dbuf; V0 -> Vs[0]
#pragma unroll
  for (int g = 0; g < 2; ++g)
    gload_lds16(Qm + (size_t)(rb + q0 + wave * 16 + g * 8 + srow) * Dd + cb0 + scol,
                ksflat + (wave * 2 + g) * 512);
  gload_lds16(vg, vsl);
  __syncthreads();

  constexpr float SCL = 0.25f * 1.44269504088896f;
  bf16x8 aq0 = ld_frag(ksflat + (wave * 16 + lrow) * 64 + (lk ^ swz));
  bf16x8 aq1 = ld_frag(ksflat + (wave * 16 + lrow) * 64 + ((32 + lk) ^ swz));
#pragma unroll
  for (int e = 0; e < 8; e += 2) {
    unsigned d0 = cvt_pk_bf16(SCL * bf2f((u16)aq0[e]), SCL * bf2f((u16)aq0[e + 1]));
    unsigned d1 = cvt_pk_bf16(SCL * bf2f((u16)aq1[e]), SCL * bf2f((u16)aq1[e + 1]));
    aq0[e] = (short)(d0 & 0xffff); aq0[e + 1] = (short)(d0 >> 16);
    aq1[e] = (short)(d1 & 0xffff); aq1[e + 1] = (short)(d1 >> 16);
  }
  __syncthreads();       // all waves done reading Q
  gload_lds16(kg, ksl);  // K0 over the Q staging area (Ks[0])
  __syncthreads();       // K0+V0 ready

  bf16x8 ones;
#pragma unroll
  for (int e = 0; e < 8; ++e) ones[e] = (short)0x3F80;

  f32x4 accO[4] = {};
  f32x4 acc_ps = {};

  int nb = 0;
  for (int kv0 = 0; kv0 < Ls; kv0 += 64) {
    if (kv0 + 64 < Ls) {
      int dst = (nb ^ 1) * LBUF;
      gload_lds16(kg + (size_t)(kv0 + 64) * Dd, ksl + dst);
      gload_lds16(vg + kv0 + 64, vsl + dst);
      asm volatile("s_waitcnt vmcnt(2)" ::: "memory");
    } else {
      asm volatile("s_waitcnt vmcnt(0)" ::: "memory");
    }
    __builtin_amdgcn_s_barrier();
    const u16* ks = ksflat + nb * LBUF;
    const u16* vs = vsflat + nb * LBUF;

    f32x4 s[4];
#pragma unroll
    for (int kb = 0; kb < 4; ++kb) {
      const u16* kr = ks + (kb * 16 + lrow) * 64;
      bf16x8 bk0 = ld_frag(kr + (lk ^ swz));
      bf16x8 bk1 = ld_frag(kr + ((32 + lk) ^ swz));
      f32x4 t = {};
      __builtin_amdgcn_s_setprio(1);
      t = __builtin_amdgcn_mfma_f32_16x16x32_bf16(bk0, aq0, t, 0, 0, 0);
      t = __builtin_amdgcn_mfma_f32_16x16x32_bf16(bk1, aq1, t, 0, 0, 0);
      __builtin_amdgcn_s_setprio(0);
      s[kb] = t;
    }

    unsigned u00 = cvt_pk_bf16(__builtin_amdgcn_exp2f(s[0][0]), __builtin_amdgcn_exp2f(s[0][1]));
    unsigned u01 = cvt_pk_bf16(__builtin_amdgcn_exp2f(s[0][2]), __builtin_amdgcn_exp2f(s[0][3]));
    unsigned u10 = cvt_pk_bf16(__builtin_amdgcn_exp2f(s[1][0]), __builtin_amdgcn_exp2f(s[1][1]));
    unsigned u11 = cvt_pk_bf16(__builtin_amdgcn_exp2f(s[1][2]), __builtin_amdgcn_exp2f(s[1][3]));
    unsigned u20 = cvt_pk_bf16(__builtin_amdgcn_exp2f(s[2][0]), __builtin_amdgcn_exp2f(s[2][1]));
    unsigned u21 = cvt_pk_bf16(__builtin_amdgcn_exp2f(s[2][2]), __builtin_amdgcn_exp2f(s[2][3]));
    unsigned u30 = cvt_pk_bf16(__builtin_amdgcn_exp2f(s[3][0]), __builtin_amdgcn_exp2f(s[3][1]));
    unsigned u31 = cvt_pk_bf16(__builtin_amdgcn_exp2f(s[3][2]), __builtin_amdgcn_exp2f(s[3][3]));

    asm("v_permlane32_swap_b32 %0, %1" : "+v"(u00), "+v"(u10));
    asm("v_permlane16_swap_b32 %0, %1" : "+v"(u00), "+v"(u10));
    asm("v_permlane32_swap_b32 %0, %1" : "+v"(u01), "+v"(u11));
    asm("v_permlane16_swap_b32 %0, %1" : "+v"(u01), "+v"(u11));
    asm("v_permlane32_swap_b32 %0, %1" : "+v"(u20), "+v"(u30));
    asm("v_permlane16_swap_b32 %0, %1" : "+v"(u20), "+v"(u30));
    asm("v_permlane32_swap_b32 %0, %1" : "+v"(u21), "+v"(u31));
    asm("v_permlane16_swap_b32 %0, %1" : "+v"(u21), "+v"(u31));

    union { unsigned u[4]; bf16x8 v; } apc0, apc1;
    apc0.u[0] = u00; apc0.u[1] = u01; apc0.u[2] = u10; apc0.u[3] = u11;
    apc1.u[0] = u20; apc1.u[1] = u21; apc1.u[2] = u30; apc1.u[3] = u31;

#pragma unroll
    for (int kk2 = 0; kk2 < 2; ++kk2) {
      bf16x8 ap = kk2 == 0 ? apc0.v : apc1.v;
      __builtin_amdgcn_s_setprio(1);
#pragma unroll
      for (int cb = 0; cb < 4; ++cb) {
        const u16* vr = vs + (cb * 16 + lrow) * 64;
        bf16x8 bv = ld_frag(vr + ((kk2 * 32 + lk) ^ swz));
        accO[cb] = __builtin_amdgcn_mfma_f32_16x16x32_bf16(bv, ap, accO[cb], 0, 0, 0);
      }
      acc_ps = __builtin_amdgcn_mfma_f32_16x16x32_bf16(ones, ap, acc_ps, 0, 0, 0);
      __builtin_amdgcn_s_setprio(0);
    }

    if (kv0 + 64 < Ls) __builtin_amdgcn_s_barrier();
    nb ^= 1;
  }

  float rinv = 1.0f / acc_ps[0];
  const size_t orow = (size_t)(rb + q0 + wave * 16 + lrow) * Dd + cb0;
#pragma unroll
  for (int cb = 0; cb < 4; ++cb) {
    uint2 o;
    o.x = cvt_pk_bf16(accO[cb][0] * rinv, accO[cb][1] * rinv);
    o.y = cvt_pk_bf16(accO[cb][2] * rinv, accO[cb][3] * rinv);
    *reinterpret_cast<uint2*>(&Om[orow + cb * 16 + (lk >> 1)]) = o;
  }
}

extern "C" void kernel_launch(void* const* d_in, const int* in_sizes, int n_in,
                              void* d_out, int out_size, void* d_ws, size_t ws_size,
                              hipStream_t stream) {
  (void)in_sizes; (void)n_in; (void)out_size; (void)ws_size;
  const float* x  = (const float*)d_in[0];
  const float* wq = (const float*)d_in[1];
  const float* bq = (const float*)d_in[2];
  const float* wk = (const float*)d_in[3];
  const float* bk = (const float*)d_in[4];
  const float* wv = (const float*)d_in[5];
  const float* bv = (const float*)d_in[6];
  const float* wo = (const float*)d_in[7];
  const float* bo = (const float*)d_in[8];
  float* out = (float*)d_out;

  u16* ws  = (u16*)d_ws;
  u16* xb  = ws;                          // 8192x1024 (x bf16; reused as attn out)
  u16* wqb = xb  + (size_t)Mm * Dd;       // 1024x1024 each; wq,wk,wv CONTIGUOUS
  u16* wkb = wqb + (size_t)Dd * Dd;
  u16* wvb = wkb + (size_t)Dd * Dd;
  u16* wob = wvb + (size_t)Dd * Dd;
  u16* qm  = wob + (size_t)Dd * Dd;       // 8192x1024
  u16* km  = qm  + (size_t)Mm * Dd;       // 8192x1024
  u16* vt  = km  + (size_t)Mm * Dd;       // 1024x8192 (V^T)
  u16* om  = xb;                          // alias: xb content dead after QKV GEMM

  cvt_all<<<2048, 256, 0, stream>>>(x, wq, wk, wv, wo, xb, wqb, wkb, wvb, wob);

  dim3 qkvgrid(3 * Dd / 256, Mm / 128);   // 12 x 64 = 768 blocks, zero tail
  gemm_qkv<<<qkvgrid, 512, 0, stream>>>(xb, wqb, bq, bk, bv, qm, km, vt);

  dim3 agrid(Bb * Hh, Ls / 128);          // 64 x 16 = 1024 blocks, 4/CU
  attn_fwd<<<agrid, 512, 0, stream>>>(qm, km, vt, om);

  dim3 ogrid(Dd / 128, Mm / 128);
  gemm_out<<<ogrid, 256, 0, stream>>>(om, wob, bo, out, Mm, Dd, Dd);
}

// Round 14
// 177.632 us; speedup vs baseline: 1.1654x; 1.0919x over previous
//
#include <hip/hip_runtime.h>
#include <hip/hip_bf16.h>

#define DEVI __device__ __forceinline__

using u16 = unsigned short;
typedef __attribute__((ext_vector_type(8))) short bf16x8;
typedef __attribute__((ext_vector_type(4))) short bf16x4;
typedef __attribute__((ext_vector_type(4))) float f32x4;

constexpr int Bb = 4, Ls = 2048, Dd = 1024, Hh = 16, DhC = 64;
constexpr int Mm = Bb * Ls; // 8192

DEVI u16 f2bf(float f) {
  union { float f; unsigned u; } x; x.f = f;
  unsigned r = x.u + 0x7FFFu + ((x.u >> 16) & 1u);
  return (u16)(r >> 16);
}
DEVI float bf2f(u16 b) {
  union { unsigned u; float f; } x; x.u = ((unsigned)b) << 16;
  return x.f;
}

// pack two f32 -> two bf16 (RTNE): D[15:0]=bf16(a), D[31:16]=bf16(b)
DEVI unsigned cvt_pk_bf16(float a, float b) {
  unsigned d;
  asm("v_cvt_pk_bf16_f32 %0, %1, %2" : "=v"(d) : "v"(a), "v"(b));
  return d;
}

DEVI void gload_lds16(const u16* g, u16* l) {
  __builtin_amdgcn_global_load_lds(
      (const __attribute__((address_space(1))) unsigned int*)g,
      (__attribute__((address_space(3))) unsigned int*)l, 16, 0, 0);
}

DEVI bf16x8 ld_frag(const u16* p) { return *reinterpret_cast<const bf16x8*>(p); }

// single launch: x (8192x1024) + all four 1024x1024 weights
__global__ void cvt_all(const float* __restrict__ x,
                        const float* __restrict__ wq, const float* __restrict__ wk,
                        const float* __restrict__ wv, const float* __restrict__ wo,
                        u16* __restrict__ xb,
                        u16* __restrict__ wqb, u16* __restrict__ wkb,
                        u16* __restrict__ wvb, u16* __restrict__ wob) {
  const int tid = blockIdx.x * blockDim.x + threadIdx.x;  // grid 2048 x 256
  constexpr int NT = 2048 * 256;
  constexpr int N4X = Mm * Dd / 4;       // 2M float4
  constexpr int N4W = Dd * Dd / 4;       // 256K float4 per weight
  for (int i = tid; i < N4X; i += NT) {
    float4 v = reinterpret_cast<const float4*>(x)[i];
    reinterpret_cast<ushort4*>(xb)[i] =
        make_ushort4(f2bf(v.x), f2bf(v.y), f2bf(v.z), f2bf(v.w));
  }
  for (int i = tid; i < 4 * N4W; i += NT) {
    int which = i / N4W, off = i - which * N4W;
    const float* s = which == 0 ? wq : which == 1 ? wk : which == 2 ? wv : wo;
    u16* d = which == 0 ? wqb : which == 1 ? wkb : which == 2 ? wvb : wob;
    float4 v = reinterpret_cast<const float4*>(s)[off];
    reinterpret_cast<ushort4*>(d)[off] =
        make_ushort4(f2bf(v.x), f2bf(v.y), f2bf(v.z), f2bf(v.w));
  }
}

// Fused QKV projection, 128x256 2-phase zero-tail schedule (R13, unchanged).
__global__ __launch_bounds__(512) void gemm_qkv(
    const u16* __restrict__ A, const u16* __restrict__ W,
    const float* __restrict__ bq, const float* __restrict__ bk2,
    const float* __restrict__ bv,
    u16* __restrict__ qm, u16* __restrict__ km, u16* __restrict__ vt)
{
  constexpr int K = 1024, BK = 64, NSTEP = K / BK;  // 16
  __shared__ u16 ldsA[2][128 * 64];                 // 32 KiB
  __shared__ u16 ldsB[2][256 * 64];                 // 64 KiB

  const int tid = threadIdx.x;
  const int wave = tid >> 6, lane = tid & 63;
  const int wr = wave >> 2, wc = wave & 3;          // 2M x 4N waves
  const int lrow = lane & 15, hi = lane >> 4, lk = hi * 8;
  const int swz = (lrow & 7) << 3;                  // u16-index XOR for reads

  const int lin = blockIdx.y * 12 + blockIdx.x;     // 0..767
  const int nid = (lin & 7) * 96 + (lin >> 3);      // bijective (768/8=96)
  const int bx = nid % 12, by = nid / 12;
  const int m0 = by * 128;
  const int n0g = bx * 256;                         // [0, 3072)

  int a_row[2], a_kc[2], b_row[4], b_kc[4];
#pragma unroll
  for (int g = 0; g < 2; ++g) {
    int c = g * 512 + tid;
    a_row[g] = c >> 3;
    a_kc[g] = ((c & 7) ^ (a_row[g] & 7)) * 8;
  }
#pragma unroll
  for (int g = 0; g < 4; ++g) {
    int c = g * 512 + tid;
    b_row[g] = c >> 3;
    b_kc[g] = ((c & 7) ^ (b_row[g] & 7)) * 8;
  }

  f32x4 acc[4][4] = {};

#pragma unroll
  for (int g = 0; g < 2; ++g)
    gload_lds16(A + (size_t)(m0 + a_row[g]) * K + a_kc[g], &ldsA[0][0] + (g * 512 + tid) * 8);
#pragma unroll
  for (int g = 0; g < 4; ++g)
    gload_lds16(W + (size_t)(n0g + b_row[g]) * K + b_kc[g], &ldsB[0][0] + (g * 512 + tid) * 8);
  __syncthreads();

  for (int t = 0; t < NSTEP; ++t) {
    const u16* Ab = &ldsA[t & 1][0];
    const u16* Bb = &ldsB[t & 1][0];
    u16* An = &ldsA[(t + 1) & 1][0];
    u16* Bn = &ldsB[(t + 1) & 1][0];
    const int k1 = (t + 1) * BK;
    const bool more = (t + 1 < NSTEP);

    bf16x8 a[4][2], b0[2][2], b1[2][2];

#pragma unroll
    for (int f = 0; f < 4; ++f) {
      int row = wr * 64 + f * 16 + lrow;
      a[f][0] = ld_frag(Ab + row * 64 + (lk ^ swz));
      a[f][1] = ld_frag(Ab + row * 64 + ((32 + lk) ^ swz));
    }
#pragma unroll
    for (int f = 0; f < 2; ++f) {
      int row = wc * 64 + f * 16 + lrow;
      b0[f][0] = ld_frag(Bb + row * 64 + (lk ^ swz));
      b0[f][1] = ld_frag(Bb + row * 64 + ((32 + lk) ^ swz));
    }
    if (more) {
      gload_lds16(A + (size_t)(m0 + a_row[0]) * K + k1 + a_kc[0], An + (0 * 512 + tid) * 8);
      gload_lds16(A + (size_t)(m0 + a_row[1]) * K + k1 + a_kc[1], An + (1 * 512 + tid) * 8);
      gload_lds16(W + (size_t)(n0g + b_row[0]) * K + k1 + b_kc[0], Bn + (0 * 512 + tid) * 8);
    }
    __builtin_amdgcn_s_barrier();
    __builtin_amdgcn_s_setprio(1);
#pragma unroll
    for (int fm = 0; fm < 4; ++fm)
#pragma unroll
      for (int fn = 0; fn < 2; ++fn)
#pragma unroll
        for (int kk = 0; kk < 2; ++kk)
          acc[fm][fn] = __builtin_amdgcn_mfma_f32_16x16x32_bf16(a[fm][kk], b0[fn][kk], acc[fm][fn], 0, 0, 0);
    __builtin_amdgcn_s_setprio(0);
    __builtin_amdgcn_s_barrier();

#pragma unroll
    for (int f = 0; f < 2; ++f) {
      int row = wc * 64 + (2 + f) * 16 + lrow;
      b1[f][0] = ld_frag(Bb + row * 64 + (lk ^ swz));
      b1[f][1] = ld_frag(Bb + row * 64 + ((32 + lk) ^ swz));
    }
    if (more) {
      gload_lds16(W + (size_t)(n0g + b_row[1]) * K + k1 + b_kc[1], Bn + (1 * 512 + tid) * 8);
      gload_lds16(W + (size_t)(n0g + b_row[2]) * K + k1 + b_kc[2], Bn + (2 * 512 + tid) * 8);
      gload_lds16(W + (size_t)(n0g + b_row[3]) * K + k1 + b_kc[3], Bn + (3 * 512 + tid) * 8);
    }
    __builtin_amdgcn_s_barrier();
    __builtin_amdgcn_s_setprio(1);
#pragma unroll
    for (int fm = 0; fm < 4; ++fm)
#pragma unroll
      for (int fn = 0; fn < 2; ++fn)
#pragma unroll
        for (int kk = 0; kk < 2; ++kk)
          acc[fm][2 + fn] = __builtin_amdgcn_mfma_f32_16x16x32_bf16(a[fm][kk], b1[fn][kk], acc[fm][2 + fn], 0, 0, 0);
    __builtin_amdgcn_s_setprio(0);
    if (more) asm volatile("s_waitcnt vmcnt(0)" ::: "memory");
    __builtin_amdgcn_s_barrier();
  }

  const int region = bx >> 2;               // 0=q, 1=k, 2=v
  const int nc0 = (bx & 3) * 256;
  const float* bias = region == 0 ? bq : region == 1 ? bk2 : bv;
  u16* dstRM = region == 0 ? qm : km;

#pragma unroll
  for (int fm = 0; fm < 4; ++fm) {
#pragma unroll
    for (int fn = 0; fn < 4; ++fn) {
      int row = m0 + wr * 64 + fm * 16 + hi * 4;
      int col = nc0 + wc * 64 + fn * 16 + lrow;
      float bv_ = bias[col];
      if (region == 2) {
        ushort4 o;
        o.x = f2bf(acc[fm][fn][0] + bv_); o.y = f2bf(acc[fm][fn][1] + bv_);
        o.z = f2bf(acc[fm][fn][2] + bv_); o.w = f2bf(acc[fm][fn][3] + bv_);
        *reinterpret_cast<ushort4*>(&vt[(size_t)col * Mm + row]) = o;
      } else {
#pragma unroll
        for (int j = 0; j < 4; ++j)
          dstRM[(size_t)(row + j) * Dd + col] = f2bf(acc[fm][fn][j] + bv_);
      }
    }
  }
}

// Out-projection GEMM, retiled to the same 128x256 2-phase zero-tail schedule.
// Grid 4x64 = 256 blocks = exactly 1/CU, T1 XCD swizzle. f32 output.
__global__ __launch_bounds__(512) void gemm_out(
    const u16* __restrict__ A, const u16* __restrict__ Bt,
    const float* __restrict__ bias, float* __restrict__ C)
{
  constexpr int K = 1024, N = 1024, BK = 64, NSTEP = K / BK;
  __shared__ u16 ldsA[2][128 * 64];
  __shared__ u16 ldsB[2][256 * 64];

  const int tid = threadIdx.x;
  const int wave = tid >> 6, lane = tid & 63;
  const int wr = wave >> 2, wc = wave & 3;
  const int lrow = lane & 15, hi = lane >> 4, lk = hi * 8;
  const int swz = (lrow & 7) << 3;

  const int lin = blockIdx.y * 4 + blockIdx.x;      // 0..255
  const int nid = (lin & 7) * 32 + (lin >> 3);      // bijective (256/8=32)
  const int bx = nid % 4, by = nid / 4;
  const int m0 = by * 128;
  const int n0 = bx * 256;

  int a_row[2], a_kc[2], b_row[4], b_kc[4];
#pragma unroll
  for (int g = 0; g < 2; ++g) {
    int c = g * 512 + tid;
    a_row[g] = c >> 3;
    a_kc[g] = ((c & 7) ^ (a_row[g] & 7)) * 8;
  }
#pragma unroll
  for (int g = 0; g < 4; ++g) {
    int c = g * 512 + tid;
    b_row[g] = c >> 3;
    b_kc[g] = ((c & 7) ^ (b_row[g] & 7)) * 8;
  }

  f32x4 acc[4][4] = {};

#pragma unroll
  for (int g = 0; g < 2; ++g)
    gload_lds16(A + (size_t)(m0 + a_row[g]) * K + a_kc[g], &ldsA[0][0] + (g * 512 + tid) * 8);
#pragma unroll
  for (int g = 0; g < 4; ++g)
    gload_lds16(Bt + (size_t)(n0 + b_row[g]) * K + b_kc[g], &ldsB[0][0] + (g * 512 + tid) * 8);
  __syncthreads();

  for (int t = 0; t < NSTEP; ++t) {
    const u16* Ab = &ldsA[t & 1][0];
    const u16* Bb = &ldsB[t & 1][0];
    u16* An = &ldsA[(t + 1) & 1][0];
    u16* Bn = &ldsB[(t + 1) & 1][0];
    const int k1 = (t + 1) * BK;
    const bool more = (t + 1 < NSTEP);

    bf16x8 a[4][2], b0[2][2], b1[2][2];

#pragma unroll
    for (int f = 0; f < 4; ++f) {
      int row = wr * 64 + f * 16 + lrow;
      a[f][0] = ld_frag(Ab + row * 64 + (lk ^ swz));
      a[f][1] = ld_frag(Ab + row * 64 + ((32 + lk) ^ swz));
    }
#pragma unroll
    for (int f = 0; f < 2; ++f) {
      int row = wc * 64 + f * 16 + lrow;
      b0[f][0] = ld_frag(Bb + row * 64 + (lk ^ swz));
      b0[f][1] = ld_frag(Bb + row * 64 + ((32 + lk) ^ swz));
    }
    if (more) {
      gload_lds16(A + (size_t)(m0 + a_row[0]) * K + k1 + a_kc[0], An + (0 * 512 + tid) * 8);
      gload_lds16(A + (size_t)(m0 + a_row[1]) * K + k1 + a_kc[1], An + (1 * 512 + tid) * 8);
      gload_lds16(Bt + (size_t)(n0 + b_row[0]) * K + k1 + b_kc[0], Bn + (0 * 512 + tid) * 8);
    }
    __builtin_amdgcn_s_barrier();
    __builtin_amdgcn_s_setprio(1);
#pragma unroll
    for (int fm = 0; fm < 4; ++fm)
#pragma unroll
      for (int fn = 0; fn < 2; ++fn)
#pragma unroll
        for (int kk = 0; kk < 2; ++kk)
          acc[fm][fn] = __builtin_amdgcn_mfma_f32_16x16x32_bf16(a[fm][kk], b0[fn][kk], acc[fm][fn], 0, 0, 0);
    __builtin_amdgcn_s_setprio(0);
    __builtin_amdgcn_s_barrier();

#pragma unroll
    for (int f = 0; f < 2; ++f) {
      int row = wc * 64 + (2 + f) * 16 + lrow;
      b1[f][0] = ld_frag(Bb + row * 64 + (lk ^ swz));
      b1[f][1] = ld_frag(Bb + row * 64 + ((32 + lk) ^ swz));
    }
    if (more) {
      gload_lds16(Bt + (size_t)(n0 + b_row[1]) * K + k1 + b_kc[1], Bn + (1 * 512 + tid) * 8);
      gload_lds16(Bt + (size_t)(n0 + b_row[2]) * K + k1 + b_kc[2], Bn + (2 * 512 + tid) * 8);
      gload_lds16(Bt + (size_t)(n0 + b_row[3]) * K + k1 + b_kc[3], Bn + (3 * 512 + tid) * 8);
    }
    __builtin_amdgcn_s_barrier();
    __builtin_amdgcn_s_setprio(1);
#pragma unroll
    for (int fm = 0; fm < 4; ++fm)
#pragma unroll
      for (int fn = 0; fn < 2; ++fn)
#pragma unroll
        for (int kk = 0; kk < 2; ++kk)
          acc[fm][2 + fn] = __builtin_amdgcn_mfma_f32_16x16x32_bf16(a[fm][kk], b1[fn][kk], acc[fm][2 + fn], 0, 0, 0);
    __builtin_amdgcn_s_setprio(0);
    if (more) asm volatile("s_waitcnt vmcnt(0)" ::: "memory");
    __builtin_amdgcn_s_barrier();
  }

#pragma unroll
  for (int fm = 0; fm < 4; ++fm) {
#pragma unroll
    for (int fn = 0; fn < 4; ++fn) {
      int row = m0 + wr * 64 + fm * 16 + hi * 4;
      int col = n0 + wc * 64 + fn * 16 + lrow;
      float bv = bias[col];
#pragma unroll
      for (int j = 0; j < 4; ++j)
        C[(size_t)(row + j) * N + col] = acc[fm][fn][j] + bv;
    }
  }
}

// Flash attention. THIS ROUND: 2 q-blocks per wave (QBLK=256) — K fragments
// read ONCE into regs feed both q-blocks' QK^T; each V fragment read feeds
// 2 PV MFMAs. LDS-read bytes per output HALVED (R13 analysis: 512KB/iter/CU
// LDS reads > 256B/cyc port capacity -> LDS-BW-bound). Register lifetime:
// softmax(t0) runs before QK(t1) so s0 dies before s1 lives (~112 peak).
// Grid 64x8 = 512 blocks = exactly 2/CU. Loop/sync structure = R13.
__global__ __launch_bounds__(512) void attn_fwd(
    const u16* __restrict__ Qm, const u16* __restrict__ Km,
    const u16* __restrict__ Vt, u16* __restrict__ Om)
{
  __shared__ u16 Ks[2][4096];      // K dbuf; with Vs = 32KB Q staging area
  __shared__ u16 Vs[2][4096];      // V^T dbuf: [dh][key], XOR-swizzled

  const int tid = threadIdx.x;
  const int wave = tid >> 6, lane = tid & 63;  // 8 waves
  const int lrow = lane & 15, lk = (lane >> 4) * 8;
  const int swz = (lrow & 7) << 3;
  const int b = blockIdx.x >> 4, h = blockIdx.x & 15;
  const int rb = b * Ls;
  const int cb0 = h * DhC;
  const int q0 = blockIdx.y * 256;
  const int srow = lane >> 3;
  const int scol = ((lane & 7) ^ srow) * 8;   // pre-swizzled source chunk

  const u16* kg = Km + (size_t)(rb + wave * 8 + srow) * Dd + cb0 + scol;
  const u16* vg = Vt + (size_t)(cb0 + wave * 8 + srow) * Mm + rb + scol;
  u16* ksflat = &Ks[0][0];
  u16* vsflat = &Vs[0][0];
  u16* ksl = ksflat + wave * 512;
  u16* vsl = vsflat + wave * 512;
  constexpr int LBUF = 4096;

  // prologue: Q (256x64 = 32KB) -> Ks dbuf (rows 0-127) + Vs dbuf (rows 128-255)
#pragma unroll
  for (int g = 0; g < 4; ++g) {
    int c = wave * 4 + g;                     // 0..31 chunks of 512 u16
    u16* dst = c < 16 ? ksflat + c * 512 : vsflat + (c - 16) * 512;
    gload_lds16(Qm + (size_t)(rb + q0 + c * 8 + srow) * Dd + cb0 + scol, dst);
  }
  __syncthreads();

  // Q fragments (2 q-blocks x 16 rows), pre-scaled by 0.25*log2(e)
  constexpr float SCL = 0.25f * 1.44269504088896f;
  bf16x8 aq[2][2];
#pragma unroll
  for (int t = 0; t < 2; ++t) {
    int row = wave * 32 + t * 16 + lrow;      // 0..255
    const u16* base = row < 128 ? ksflat + row * 64 : vsflat + (row - 128) * 64;
    aq[t][0] = ld_frag(base + (lk ^ swz));
    aq[t][1] = ld_frag(base + ((32 + lk) ^ swz));
#pragma unroll
    for (int e = 0; e < 8; e += 2) {
      unsigned d0 = cvt_pk_bf16(SCL * bf2f((u16)aq[t][0][e]), SCL * bf2f((u16)aq[t][0][e + 1]));
      unsigned d1 = cvt_pk_bf16(SCL * bf2f((u16)aq[t][1][e]), SCL * bf2f((u16)aq[t][1][e + 1]));
      aq[t][0][e] = (short)(d0 & 0xffff); aq[t][0][e + 1] = (short)(d0 >> 16);
      aq[t][1][e] = (short)(d1 & 0xffff); aq[t][1][e + 1] = (short)(d1 >> 16);
    }
  }
  __syncthreads();       // all waves done reading Q
  gload_lds16(kg, ksl);  // K0, V0 over the Q staging area
  gload_lds16(vg, vsl);

  bf16x8 ones;
#pragma unroll
  for (int e = 0; e < 8; ++e) ones[e] = (short)0x3F80;

  f32x4 accO[2][4] = {};
  f32x4 acc_ps[2] = {};

// softmax+pack: s[] (f32x4[4], log2 units) -> two bf16x8 B-fragments
#define SM_PACK(SIN, AP0, AP1)                                                 \
  {                                                                            \
    unsigned u00 = cvt_pk_bf16(__builtin_amdgcn_exp2f(SIN[0][0]), __builtin_amdgcn_exp2f(SIN[0][1])); \
    unsigned u01 = cvt_pk_bf16(__builtin_amdgcn_exp2f(SIN[0][2]), __builtin_amdgcn_exp2f(SIN[0][3])); \
    unsigned u10 = cvt_pk_bf16(__builtin_amdgcn_exp2f(SIN[1][0]), __builtin_amdgcn_exp2f(SIN[1][1])); \
    unsigned u11 = cvt_pk_bf16(__builtin_amdgcn_exp2f(SIN[1][2]), __builtin_amdgcn_exp2f(SIN[1][3])); \
    unsigned u20 = cvt_pk_bf16(__builtin_amdgcn_exp2f(SIN[2][0]), __builtin_amdgcn_exp2f(SIN[2][1])); \
    unsigned u21 = cvt_pk_bf16(__builtin_amdgcn_exp2f(SIN[2][2]), __builtin_amdgcn_exp2f(SIN[2][3])); \
    unsigned u30 = cvt_pk_bf16(__builtin_amdgcn_exp2f(SIN[3][0]), __builtin_amdgcn_exp2f(SIN[3][1])); \
    unsigned u31 = cvt_pk_bf16(__builtin_amdgcn_exp2f(SIN[3][2]), __builtin_amdgcn_exp2f(SIN[3][3])); \
    asm("v_permlane32_swap_b32 %0, %1" : "+v"(u00), "+v"(u10));                \
    asm("v_permlane16_swap_b32 %0, %1" : "+v"(u00), "+v"(u10));                \
    asm("v_permlane32_swap_b32 %0, %1" : "+v"(u01), "+v"(u11));                \
    asm("v_permlane16_swap_b32 %0, %1" : "+v"(u01), "+v"(u11));                \
    asm("v_permlane32_swap_b32 %0, %1" : "+v"(u20), "+v"(u30));                \
    asm("v_permlane16_swap_b32 %0, %1" : "+v"(u20), "+v"(u30));                \
    asm("v_permlane32_swap_b32 %0, %1" : "+v"(u21), "+v"(u31));                \
    asm("v_permlane16_swap_b32 %0, %1" : "+v"(u21), "+v"(u31));                \
    union { unsigned u[4]; bf16x8 v; } c0_, c1_;                               \
    c0_.u[0] = u00; c0_.u[1] = u01; c0_.u[2] = u10; c0_.u[3] = u11;            \
    c1_.u[0] = u20; c1_.u[1] = u21; c1_.u[2] = u30; c1_.u[3] = u31;            \
    AP0 = c0_.v; AP1 = c1_.v;                                                  \
  }

  int nb = 0;
  for (int kv0 = 0; kv0 < Ls; kv0 += 64) {
    if (kv0 + 64 < Ls) {
      int dst = (nb ^ 1) * LBUF;
      gload_lds16(kg + (size_t)(kv0 + 64) * Dd, ksl + dst);
      gload_lds16(vg + kv0 + 64, vsl + dst);
      asm volatile("s_waitcnt vmcnt(2)" ::: "memory");
    } else {
      asm volatile("s_waitcnt vmcnt(0)" ::: "memory");
    }
    __builtin_amdgcn_s_barrier();
    const u16* ks = ksflat + nb * LBUF;
    const u16* vs = vsflat + nb * LBUF;

    // K fragments once -> registers; feed both q-blocks
    bf16x8 bk[4][2];
#pragma unroll
    for (int kb = 0; kb < 4; ++kb) {
      const u16* kr = ks + (kb * 16 + lrow) * 64;
      bk[kb][0] = ld_frag(kr + (lk ^ swz));
      bk[kb][1] = ld_frag(kr + ((32 + lk) ^ swz));
    }

    bf16x8 ap0[2], ap1[2];

    // QK t0 -> softmax t0 (frees s0 before s1 lives)
    {
      f32x4 s[4];
      __builtin_amdgcn_s_setprio(1);
#pragma unroll
      for (int kb = 0; kb < 4; ++kb) {
        f32x4 u = {};
        u = __builtin_amdgcn_mfma_f32_16x16x32_bf16(bk[kb][0], aq[0][0], u, 0, 0, 0);
        u = __builtin_amdgcn_mfma_f32_16x16x32_bf16(bk[kb][1], aq[0][1], u, 0, 0, 0);
        s[kb] = u;
      }
      __builtin_amdgcn_s_setprio(0);
      SM_PACK(s, ap0[0], ap0[1]);
    }
    // QK t1 -> softmax t1
    {
      f32x4 s[4];
      __builtin_amdgcn_s_setprio(1);
#pragma unroll
      for (int kb = 0; kb < 4; ++kb) {
        f32x4 u = {};
        u = __builtin_amdgcn_mfma_f32_16x16x32_bf16(bk[kb][0], aq[1][0], u, 0, 0, 0);
        u = __builtin_amdgcn_mfma_f32_16x16x32_bf16(bk[kb][1], aq[1][1], u, 0, 0, 0);
        s[kb] = u;
      }
      __builtin_amdgcn_s_setprio(0);
      SM_PACK(s, ap1[0], ap1[1]);
    }

    // PV for both q-blocks: each V fragment read feeds 2 MFMAs
#pragma unroll
    for (int kk2 = 0; kk2 < 2; ++kk2) {
      __builtin_amdgcn_s_setprio(1);
#pragma unroll
      for (int cb = 0; cb < 4; ++cb) {
        const u16* vr = vs + (cb * 16 + lrow) * 64;
        bf16x8 bv = ld_frag(vr + ((kk2 * 32 + lk) ^ swz));
        accO[0][cb] = __builtin_amdgcn_mfma_f32_16x16x32_bf16(bv, ap0[kk2], accO[0][cb], 0, 0, 0);
        accO[1][cb] = __builtin_amdgcn_mfma_f32_16x16x32_bf16(bv, ap1[kk2], accO[1][cb], 0, 0, 0);
      }
      acc_ps[0] = __builtin_amdgcn_mfma_f32_16x16x32_bf16(ones, ap0[kk2], acc_ps[0], 0, 0, 0);
      acc_ps[1] = __builtin_amdgcn_mfma_f32_16x16x32_bf16(ones, ap1[kk2], acc_ps[1], 0, 0, 0);
      __builtin_amdgcn_s_setprio(0);
    }

    if (kv0 + 64 < Ls) __builtin_amdgcn_s_barrier();
    nb ^= 1;
  }
#undef SM_PACK

  // epilogue: both q-blocks
#pragma unroll
  for (int t = 0; t < 2; ++t) {
    float rinv = 1.0f / acc_ps[t][0];
    const size_t orow = (size_t)(rb + q0 + wave * 32 + t * 16 + lrow) * Dd + cb0;
#pragma unroll
    for (int cb = 0; cb < 4; ++cb) {
      uint2 o;
      o.x = cvt_pk_bf16(accO[t][cb][0] * rinv, accO[t][cb][1] * rinv);
      o.y = cvt_pk_bf16(accO[t][cb][2] * rinv, accO[t][cb][3] * rinv);
      *reinterpret_cast<uint2*>(&Om[orow + cb * 16 + (lk >> 1)]) = o;
    }
  }
}

extern "C" void kernel_launch(void* const* d_in, const int* in_sizes, int n_in,
                              void* d_out, int out_size, void* d_ws, size_t ws_size,
                              hipStream_t stream) {
  (void)in_sizes; (void)n_in; (void)out_size; (void)ws_size;
  const float* x  = (const float*)d_in[0];
  const float* wq = (const float*)d_in[1];
  const float* bq = (const float*)d_in[2];
  const float* wk = (const float*)d_in[3];
  const float* bk = (const float*)d_in[4];
  const float* wv = (const float*)d_in[5];
  const float* bv = (const float*)d_in[6];
  const float* wo = (const float*)d_in[7];
  const float* bo = (const float*)d_in[8];
  float* out = (float*)d_out;

  u16* ws  = (u16*)d_ws;
  u16* xb  = ws;                          // 8192x1024 (x bf16; reused as attn out)
  u16* wqb = xb  + (size_t)Mm * Dd;       // 1024x1024 each; wq,wk,wv CONTIGUOUS
  u16* wkb = wqb + (size_t)Dd * Dd;
  u16* wvb = wkb + (size_t)Dd * Dd;
  u16* wob = wvb + (size_t)Dd * Dd;
  u16* qm  = wob + (size_t)Dd * Dd;       // 8192x1024
  u16* km  = qm  + (size_t)Mm * Dd;       // 8192x1024
  u16* vt  = km  + (size_t)Mm * Dd;       // 1024x8192 (V^T)
  u16* om  = xb;                          // alias: xb content dead after QKV GEMM

  cvt_all<<<2048, 256, 0, stream>>>(x, wq, wk, wv, wo, xb, wqb, wkb, wvb, wob);

  dim3 qkvgrid(3 * Dd / 256, Mm / 128);   // 12 x 64 = 768 blocks, zero tail
  gemm_qkv<<<qkvgrid, 512, 0, stream>>>(xb, wqb, bq, bk, bv, qm, km, vt);

  dim3 agrid(Bb * Hh, Ls / 256);          // 64 x 8 = 512 blocks, 2/CU
  attn_fwd<<<agrid, 512, 0, stream>>>(qm, km, vt, om);

  dim3 ogrid(Dd / 256, Mm / 128);         // 4 x 64 = 256 blocks, 1/CU
  gemm_out<<<ogrid, 512, 0, stream>>>(om, wob, bo, out);
}

// Round 15
// 169.397 us; speedup vs baseline: 1.2221x; 1.0486x over previous
//
#include <hip/hip_runtime.h>
#include <hip/hip_bf16.h>

#define DEVI __device__ __forceinline__

using u16 = unsigned short;
typedef __attribute__((ext_vector_type(8))) short bf16x8;
typedef __attribute__((ext_vector_type(4))) short bf16x4;
typedef __attribute__((ext_vector_type(4))) float f32x4;

constexpr int Bb = 4, Ls = 2048, Dd = 1024, Hh = 16, DhC = 64;
constexpr int Mm = Bb * Ls; // 8192

DEVI u16 f2bf(float f) {
  union { float f; unsigned u; } x; x.f = f;
  unsigned r = x.u + 0x7FFFu + ((x.u >> 16) & 1u);
  return (u16)(r >> 16);
}
DEVI float bf2f(u16 b) {
  union { unsigned u; float f; } x; x.u = ((unsigned)b) << 16;
  return x.f;
}

// pack two f32 -> two bf16 (RTNE): D[15:0]=bf16(a), D[31:16]=bf16(b)
DEVI unsigned cvt_pk_bf16(float a, float b) {
  unsigned d;
  asm("v_cvt_pk_bf16_f32 %0, %1, %2" : "=v"(d) : "v"(a), "v"(b));
  return d;
}

DEVI void gload_lds16(const u16* g, u16* l) {
  __builtin_amdgcn_global_load_lds(
      (const __attribute__((address_space(1))) unsigned int*)g,
      (__attribute__((address_space(3))) unsigned int*)l, 16, 0, 0);
}

DEVI bf16x8 ld_frag(const u16* p) { return *reinterpret_cast<const bf16x8*>(p); }

// single launch: x (8192x1024) + all four 1024x1024 weights
__global__ void cvt_all(const float* __restrict__ x,
                        const float* __restrict__ wq, const float* __restrict__ wk,
                        const float* __restrict__ wv, const float* __restrict__ wo,
                        u16* __restrict__ xb,
                        u16* __restrict__ wqb, u16* __restrict__ wkb,
                        u16* __restrict__ wvb, u16* __restrict__ wob) {
  const int tid = blockIdx.x * blockDim.x + threadIdx.x;  // grid 2048 x 256
  constexpr int NT = 2048 * 256;
  constexpr int N4X = Mm * Dd / 4;
  constexpr int N4W = Dd * Dd / 4;
  for (int i = tid; i < N4X; i += NT) {
    float4 v = reinterpret_cast<const float4*>(x)[i];
    reinterpret_cast<ushort4*>(xb)[i] =
        make_ushort4(f2bf(v.x), f2bf(v.y), f2bf(v.z), f2bf(v.w));
  }
  for (int i = tid; i < 4 * N4W; i += NT) {
    int which = i / N4W, off = i - which * N4W;
    const float* s = which == 0 ? wq : which == 1 ? wk : which == 2 ? wv : wo;
    u16* d = which == 0 ? wqb : which == 1 ? wkb : which == 2 ? wvb : wob;
    float4 v = reinterpret_cast<const float4*>(s)[off];
    reinterpret_cast<ushort4*>(d)[off] =
        make_ushort4(f2bf(v.x), f2bf(v.y), f2bf(v.z), f2bf(v.w));
  }
}

// Fused QKV projection, 128x256 2-phase zero-tail schedule + TRIPLE-buffered
// LDS (144KB): stage tile t+2 during step t; end-of-step wait is vmcnt(6)
// (the 6 loads of t+2 stay in flight; in-order retirement guarantees tile
// t+1 landed) — staging latency gets ~2 K-steps to hide instead of ~1 phase.
// WAR: buf (t+2)%3 was last read in step t-1, whose end barrier precedes
// this step's stage issue.
__global__ __launch_bounds__(512) void gemm_qkv(
    const u16* __restrict__ A, const u16* __restrict__ W,
    const float* __restrict__ bq, const float* __restrict__ bk2,
    const float* __restrict__ bv,
    u16* __restrict__ qm, u16* __restrict__ km, u16* __restrict__ vt)
{
  constexpr int K = 1024, BK = 64, NSTEP = K / BK;  // 16
  __shared__ u16 ldsA[3][128 * 64];                 // 48 KiB
  __shared__ u16 ldsB[3][256 * 64];                 // 96 KiB

  const int tid = threadIdx.x;
  const int wave = tid >> 6, lane = tid & 63;
  const int wr = wave >> 2, wc = wave & 3;          // 2M x 4N waves
  const int lrow = lane & 15, hi = lane >> 4, lk = hi * 8;
  const int swz = (lrow & 7) << 3;

  const int lin = blockIdx.y * 12 + blockIdx.x;     // 0..767
  const int nid = (lin & 7) * 96 + (lin >> 3);      // bijective (768/8=96)
  const int bx = nid % 12, by = nid / 12;
  const int m0 = by * 128;
  const int n0g = bx * 256;

  int a_row[2], a_kc[2], b_row[4], b_kc[4];
#pragma unroll
  for (int g = 0; g < 2; ++g) {
    int c = g * 512 + tid;
    a_row[g] = c >> 3;
    a_kc[g] = ((c & 7) ^ (a_row[g] & 7)) * 8;
  }
#pragma unroll
  for (int g = 0; g < 4; ++g) {
    int c = g * 512 + tid;
    b_row[g] = c >> 3;
    b_kc[g] = ((c & 7) ^ (b_row[g] & 7)) * 8;
  }

  f32x4 acc[4][4] = {};

  // prologue: stage tile0 -> buf0 and tile1 -> buf1; wait tile0 only
#pragma unroll
  for (int g = 0; g < 2; ++g)
    gload_lds16(A + (size_t)(m0 + a_row[g]) * K + a_kc[g], &ldsA[0][0] + (g * 512 + tid) * 8);
#pragma unroll
  for (int g = 0; g < 4; ++g)
    gload_lds16(W + (size_t)(n0g + b_row[g]) * K + b_kc[g], &ldsB[0][0] + (g * 512 + tid) * 8);
#pragma unroll
  for (int g = 0; g < 2; ++g)
    gload_lds16(A + (size_t)(m0 + a_row[g]) * K + BK + a_kc[g], &ldsA[1][0] + (g * 512 + tid) * 8);
#pragma unroll
  for (int g = 0; g < 4; ++g)
    gload_lds16(W + (size_t)(n0g + b_row[g]) * K + BK + b_kc[g], &ldsB[1][0] + (g * 512 + tid) * 8);
  asm volatile("s_waitcnt vmcnt(6)" ::: "memory");
  __syncthreads();

  int cur = 0, nx2 = 2;   // t%3, (t+2)%3
  for (int t = 0; t < NSTEP; ++t) {
    const u16* Ab = &ldsA[cur][0];
    const u16* Bb = &ldsB[cur][0];
    u16* An = &ldsA[nx2][0];
    u16* Bn = &ldsB[nx2][0];
    const int k2 = (t + 2) * BK;
    const bool more2 = (t + 2 < NSTEP);

    bf16x8 a[4][2], b0[2][2], b1[2][2];

    // ---- phase 0
#pragma unroll
    for (int f = 0; f < 4; ++f) {
      int row = wr * 64 + f * 16 + lrow;
      a[f][0] = ld_frag(Ab + row * 64 + (lk ^ swz));
      a[f][1] = ld_frag(Ab + row * 64 + ((32 + lk) ^ swz));
    }
#pragma unroll
    for (int f = 0; f < 2; ++f) {
      int row = wc * 64 + f * 16 + lrow;
      b0[f][0] = ld_frag(Bb + row * 64 + (lk ^ swz));
      b0[f][1] = ld_frag(Bb + row * 64 + ((32 + lk) ^ swz));
    }
    if (more2) {
      gload_lds16(A + (size_t)(m0 + a_row[0]) * K + k2 + a_kc[0], An + (0 * 512 + tid) * 8);
      gload_lds16(A + (size_t)(m0 + a_row[1]) * K + k2 + a_kc[1], An + (1 * 512 + tid) * 8);
      gload_lds16(W + (size_t)(n0g + b_row[0]) * K + k2 + b_kc[0], Bn + (0 * 512 + tid) * 8);
    }
    __builtin_amdgcn_s_barrier();
    __builtin_amdgcn_s_setprio(1);
#pragma unroll
    for (int fm = 0; fm < 4; ++fm)
#pragma unroll
      for (int fn = 0; fn < 2; ++fn)
#pragma unroll
        for (int kk = 0; kk < 2; ++kk)
          acc[fm][fn] = __builtin_amdgcn_mfma_f32_16x16x32_bf16(a[fm][kk], b0[fn][kk], acc[fm][fn], 0, 0, 0);
    __builtin_amdgcn_s_setprio(0);
    __builtin_amdgcn_s_barrier();

    // ---- phase 1
#pragma unroll
    for (int f = 0; f < 2; ++f) {
      int row = wc * 64 + (2 + f) * 16 + lrow;
      b1[f][0] = ld_frag(Bb + row * 64 + (lk ^ swz));
      b1[f][1] = ld_frag(Bb + row * 64 + ((32 + lk) ^ swz));
    }
    if (more2) {
      gload_lds16(W + (size_t)(n0g + b_row[1]) * K + k2 + b_kc[1], Bn + (1 * 512 + tid) * 8);
      gload_lds16(W + (size_t)(n0g + b_row[2]) * K + k2 + b_kc[2], Bn + (2 * 512 + tid) * 8);
      gload_lds16(W + (size_t)(n0g + b_row[3]) * K + k2 + b_kc[3], Bn + (3 * 512 + tid) * 8);
    }
    __builtin_amdgcn_s_barrier();
    __builtin_amdgcn_s_setprio(1);
#pragma unroll
    for (int fm = 0; fm < 4; ++fm)
#pragma unroll
      for (int fn = 0; fn < 2; ++fn)
#pragma unroll
        for (int kk = 0; kk < 2; ++kk)
          acc[fm][2 + fn] = __builtin_amdgcn_mfma_f32_16x16x32_bf16(a[fm][kk], b1[fn][kk], acc[fm][2 + fn], 0, 0, 0);
    __builtin_amdgcn_s_setprio(0);
    // end of K-step: ensure tile t+1 landed; t+2's 6 loads stay in flight
    if (t + 1 < NSTEP) {
      if (more2) asm volatile("s_waitcnt vmcnt(6)" ::: "memory");
      else       asm volatile("s_waitcnt vmcnt(0)" ::: "memory");
    }
    __builtin_amdgcn_s_barrier();
    cur = cur == 2 ? 0 : cur + 1;
    nx2 = nx2 == 2 ? 0 : nx2 + 1;
  }

  const int region = bx >> 2;               // 0=q, 1=k, 2=v
  const int nc0 = (bx & 3) * 256;
  const float* bias = region == 0 ? bq : region == 1 ? bk2 : bv;
  u16* dstRM = region == 0 ? qm : km;

#pragma unroll
  for (int fm = 0; fm < 4; ++fm) {
#pragma unroll
    for (int fn = 0; fn < 4; ++fn) {
      int row = m0 + wr * 64 + fm * 16 + hi * 4;
      int col = nc0 + wc * 64 + fn * 16 + lrow;
      float bv_ = bias[col];
      if (region == 2) {
        ushort4 o;
        o.x = f2bf(acc[fm][fn][0] + bv_); o.y = f2bf(acc[fm][fn][1] + bv_);
        o.z = f2bf(acc[fm][fn][2] + bv_); o.w = f2bf(acc[fm][fn][3] + bv_);
        *reinterpret_cast<ushort4*>(&vt[(size_t)col * Mm + row]) = o;
      } else {
#pragma unroll
        for (int j = 0; j < 4; ++j)
          dstRM[(size_t)(row + j) * Dd + col] = f2bf(acc[fm][fn][j] + bv_);
      }
    }
  }
}

// Out-projection GEMM: same 128x256 2-phase + triple-buffer. f32 out.
__global__ __launch_bounds__(512) void gemm_out(
    const u16* __restrict__ A, const u16* __restrict__ Bt,
    const float* __restrict__ bias, float* __restrict__ C)
{
  constexpr int K = 1024, N = 1024, BK = 64, NSTEP = K / BK;
  __shared__ u16 ldsA[3][128 * 64];
  __shared__ u16 ldsB[3][256 * 64];

  const int tid = threadIdx.x;
  const int wave = tid >> 6, lane = tid & 63;
  const int wr = wave >> 2, wc = wave & 3;
  const int lrow = lane & 15, hi = lane >> 4, lk = hi * 8;
  const int swz = (lrow & 7) << 3;

  const int lin = blockIdx.y * 4 + blockIdx.x;      // 0..255
  const int nid = (lin & 7) * 32 + (lin >> 3);      // bijective (256/8=32)
  const int bx = nid % 4, by = nid / 4;
  const int m0 = by * 128;
  const int n0 = bx * 256;

  int a_row[2], a_kc[2], b_row[4], b_kc[4];
#pragma unroll
  for (int g = 0; g < 2; ++g) {
    int c = g * 512 + tid;
    a_row[g] = c >> 3;
    a_kc[g] = ((c & 7) ^ (a_row[g] & 7)) * 8;
  }
#pragma unroll
  for (int g = 0; g < 4; ++g) {
    int c = g * 512 + tid;
    b_row[g] = c >> 3;
    b_kc[g] = ((c & 7) ^ (b_row[g] & 7)) * 8;
  }

  f32x4 acc[4][4] = {};

#pragma unroll
  for (int g = 0; g < 2; ++g)
    gload_lds16(A + (size_t)(m0 + a_row[g]) * K + a_kc[g], &ldsA[0][0] + (g * 512 + tid) * 8);
#pragma unroll
  for (int g = 0; g < 4; ++g)
    gload_lds16(Bt + (size_t)(n0 + b_row[g]) * K + b_kc[g], &ldsB[0][0] + (g * 512 + tid) * 8);
#pragma unroll
  for (int g = 0; g < 2; ++g)
    gload_lds16(A + (size_t)(m0 + a_row[g]) * K + BK + a_kc[g], &ldsA[1][0] + (g * 512 + tid) * 8);
#pragma unroll
  for (int g = 0; g < 4; ++g)
    gload_lds16(Bt + (size_t)(n0 + b_row[g]) * K + BK + b_kc[g], &ldsB[1][0] + (g * 512 + tid) * 8);
  asm volatile("s_waitcnt vmcnt(6)" ::: "memory");
  __syncthreads();

  int cur = 0, nx2 = 2;
  for (int t = 0; t < NSTEP; ++t) {
    const u16* Ab = &ldsA[cur][0];
    const u16* Bb = &ldsB[cur][0];
    u16* An = &ldsA[nx2][0];
    u16* Bn = &ldsB[nx2][0];
    const int k2 = (t + 2) * BK;
    const bool more2 = (t + 2 < NSTEP);

    bf16x8 a[4][2], b0[2][2], b1[2][2];

#pragma unroll
    for (int f = 0; f < 4; ++f) {
      int row = wr * 64 + f * 16 + lrow;
      a[f][0] = ld_frag(Ab + row * 64 + (lk ^ swz));
      a[f][1] = ld_frag(Ab + row * 64 + ((32 + lk) ^ swz));
    }
#pragma unroll
    for (int f = 0; f < 2; ++f) {
      int row = wc * 64 + f * 16 + lrow;
      b0[f][0] = ld_frag(Bb + row * 64 + (lk ^ swz));
      b0[f][1] = ld_frag(Bb + row * 64 + ((32 + lk) ^ swz));
    }
    if (more2) {
      gload_lds16(A + (size_t)(m0 + a_row[0]) * K + k2 + a_kc[0], An + (0 * 512 + tid) * 8);
      gload_lds16(A + (size_t)(m0 + a_row[1]) * K + k2 + a_kc[1], An + (1 * 512 + tid) * 8);
      gload_lds16(Bt + (size_t)(n0 + b_row[0]) * K + k2 + b_kc[0], Bn + (0 * 512 + tid) * 8);
    }
    __builtin_amdgcn_s_barrier();
    __builtin_amdgcn_s_setprio(1);
#pragma unroll
    for (int fm = 0; fm < 4; ++fm)
#pragma unroll
      for (int fn = 0; fn < 2; ++fn)
#pragma unroll
        for (int kk = 0; kk < 2; ++kk)
          acc[fm][fn] = __builtin_amdgcn_mfma_f32_16x16x32_bf16(a[fm][kk], b0[fn][kk], acc[fm][fn], 0, 0, 0);
    __builtin_amdgcn_s_setprio(0);
    __builtin_amdgcn_s_barrier();

#pragma unroll
    for (int f = 0; f < 2; ++f) {
      int row = wc * 64 + (2 + f) * 16 + lrow;
      b1[f][0] = ld_frag(Bb + row * 64 + (lk ^ swz));
      b1[f][1] = ld_frag(Bb + row * 64 + ((32 + lk) ^ swz));
    }
    if (more2) {
      gload_lds16(Bt + (size_t)(n0 + b_row[1]) * K + k2 + b_kc[1], Bn + (1 * 512 + tid) * 8);
      gload_lds16(Bt + (size_t)(n0 + b_row[2]) * K + k2 + b_kc[2], Bn + (2 * 512 + tid) * 8);
      gload_lds16(Bt + (size_t)(n0 + b_row[3]) * K + k2 + b_kc[3], Bn + (3 * 512 + tid) * 8);
    }
    __builtin_amdgcn_s_barrier();
    __builtin_amdgcn_s_setprio(1);
#pragma unroll
    for (int fm = 0; fm < 4; ++fm)
#pragma unroll
      for (int fn = 0; fn < 2; ++fn)
#pragma unroll
        for (int kk = 0; kk < 2; ++kk)
          acc[fm][2 + fn] = __builtin_amdgcn_mfma_f32_16x16x32_bf16(a[fm][kk], b1[fn][kk], acc[fm][2 + fn], 0, 0, 0);
    __builtin_amdgcn_s_setprio(0);
    if (t + 1 < NSTEP) {
      if (more2) asm volatile("s_waitcnt vmcnt(6)" ::: "memory");
      else       asm volatile("s_waitcnt vmcnt(0)" ::: "memory");
    }
    __builtin_amdgcn_s_barrier();
    cur = cur == 2 ? 0 : cur + 1;
    nx2 = nx2 == 2 ? 0 : nx2 + 1;
  }

#pragma unroll
  for (int fm = 0; fm < 4; ++fm) {
#pragma unroll
    for (int fn = 0; fn < 4; ++fn) {
      int row = m0 + wr * 64 + fm * 16 + hi * 4;
      int col = n0 + wc * 64 + fn * 16 + lrow;
      float bv = bias[col];
#pragma unroll
      for (int j = 0; j < 4; ++j)
        C[(size_t)(row + j) * N + col] = acc[fm][fn][j] + bv;
    }
  }
}

// Flash attention, 2 q-blocks/wave (R14). THIS ROUND: QK(t0) and QK(t1)
// issued BACK-TO-BACK, softmax for both after — SM(t0) depends only on s0,
// so QK(t1)'s MFMAs drain on the matrix pipe while SM(t0) runs on the VALU
// (in-tile pipe overlap; no cross-iteration state). +32 transient VGPR.
__global__ __launch_bounds__(512) void attn_fwd(
    const u16* __restrict__ Qm, const u16* __restrict__ Km,
    const u16* __restrict__ Vt, u16* __restrict__ Om)
{
  __shared__ u16 Ks[2][4096];
  __shared__ u16 Vs[2][4096];

  const int tid = threadIdx.x;
  const int wave = tid >> 6, lane = tid & 63;
  const int lrow = lane & 15, lk = (lane >> 4) * 8;
  const int swz = (lrow & 7) << 3;
  const int b = blockIdx.x >> 4, h = blockIdx.x & 15;
  const int rb = b * Ls;
  const int cb0 = h * DhC;
  const int q0 = blockIdx.y * 256;
  const int srow = lane >> 3;
  const int scol = ((lane & 7) ^ srow) * 8;

  const u16* kg = Km + (size_t)(rb + wave * 8 + srow) * Dd + cb0 + scol;
  const u16* vg = Vt + (size_t)(cb0 + wave * 8 + srow) * Mm + rb + scol;
  u16* ksflat = &Ks[0][0];
  u16* vsflat = &Vs[0][0];
  u16* ksl = ksflat + wave * 512;
  u16* vsl = vsflat + wave * 512;
  constexpr int LBUF = 4096;

  // prologue: Q (256x64 = 32KB) -> Ks+Vs dbuf area
#pragma unroll
  for (int g = 0; g < 4; ++g) {
    int c = wave * 4 + g;
    u16* dst = c < 16 ? ksflat + c * 512 : vsflat + (c - 16) * 512;
    gload_lds16(Qm + (size_t)(rb + q0 + c * 8 + srow) * Dd + cb0 + scol, dst);
  }
  __syncthreads();

  constexpr float SCL = 0.25f * 1.44269504088896f;
  bf16x8 aq[2][2];
#pragma unroll
  for (int t = 0; t < 2; ++t) {
    int row = wave * 32 + t * 16 + lrow;
    const u16* base = row < 128 ? ksflat + row * 64 : vsflat + (row - 128) * 64;
    aq[t][0] = ld_frag(base + (lk ^ swz));
    aq[t][1] = ld_frag(base + ((32 + lk) ^ swz));
#pragma unroll
    for (int e = 0; e < 8; e += 2) {
      unsigned d0 = cvt_pk_bf16(SCL * bf2f((u16)aq[t][0][e]), SCL * bf2f((u16)aq[t][0][e + 1]));
      unsigned d1 = cvt_pk_bf16(SCL * bf2f((u16)aq[t][1][e]), SCL * bf2f((u16)aq[t][1][e + 1]));
      aq[t][0][e] = (short)(d0 & 0xffff); aq[t][0][e + 1] = (short)(d0 >> 16);
      aq[t][1][e] = (short)(d1 & 0xffff); aq[t][1][e + 1] = (short)(d1 >> 16);
    }
  }
  __syncthreads();
  gload_lds16(kg, ksl);
  gload_lds16(vg, vsl);

  bf16x8 ones;
#pragma unroll
  for (int e = 0; e < 8; ++e) ones[e] = (short)0x3F80;

  f32x4 accO[2][4] = {};
  f32x4 acc_ps[2] = {};

#define SM_PACK(SIN, AP0, AP1)                                                 \
  {                                                                            \
    unsigned u00 = cvt_pk_bf16(__builtin_amdgcn_exp2f(SIN[0][0]), __builtin_amdgcn_exp2f(SIN[0][1])); \
    unsigned u01 = cvt_pk_bf16(__builtin_amdgcn_exp2f(SIN[0][2]), __builtin_amdgcn_exp2f(SIN[0][3])); \
    unsigned u10 = cvt_pk_bf16(__builtin_amdgcn_exp2f(SIN[1][0]), __builtin_amdgcn_exp2f(SIN[1][1])); \
    unsigned u11 = cvt_pk_bf16(__builtin_amdgcn_exp2f(SIN[1][2]), __builtin_amdgcn_exp2f(SIN[1][3])); \
    unsigned u20 = cvt_pk_bf16(__builtin_amdgcn_exp2f(SIN[2][0]), __builtin_amdgcn_exp2f(SIN[2][1])); \
    unsigned u21 = cvt_pk_bf16(__builtin_amdgcn_exp2f(SIN[2][2]), __builtin_amdgcn_exp2f(SIN[2][3])); \
    unsigned u30 = cvt_pk_bf16(__builtin_amdgcn_exp2f(SIN[3][0]), __builtin_amdgcn_exp2f(SIN[3][1])); \
    unsigned u31 = cvt_pk_bf16(__builtin_amdgcn_exp2f(SIN[3][2]), __builtin_amdgcn_exp2f(SIN[3][3])); \
    asm("v_permlane32_swap_b32 %0, %1" : "+v"(u00), "+v"(u10));                \
    asm("v_permlane16_swap_b32 %0, %1" : "+v"(u00), "+v"(u10));                \
    asm("v_permlane32_swap_b32 %0, %1" : "+v"(u01), "+v"(u11));                \
    asm("v_permlane16_swap_b32 %0, %1" : "+v"(u01), "+v"(u11));                \
    asm("v_permlane32_swap_b32 %0, %1" : "+v"(u20), "+v"(u30));                \
    asm("v_permlane16_swap_b32 %0, %1" : "+v"(u20), "+v"(u30));                \
    asm("v_permlane32_swap_b32 %0, %1" : "+v"(u21), "+v"(u31));                \
    asm("v_permlane16_swap_b32 %0, %1" : "+v"(u21), "+v"(u31));                \
    union { unsigned u[4]; bf16x8 v; } c0_, c1_;                               \
    c0_.u[0] = u00; c0_.u[1] = u01; c0_.u[2] = u10; c0_.u[3] = u11;            \
    c1_.u[0] = u20; c1_.u[1] = u21; c1_.u[2] = u30; c1_.u[3] = u31;            \
    AP0 = c0_.v; AP1 = c1_.v;                                                  \
  }

  int nb = 0;
  for (int kv0 = 0; kv0 < Ls; kv0 += 64) {
    if (kv0 + 64 < Ls) {
      int dst = (nb ^ 1) * LBUF;
      gload_lds16(kg + (size_t)(kv0 + 64) * Dd, ksl + dst);
      gload_lds16(vg + kv0 + 64, vsl + dst);
      asm volatile("s_waitcnt vmcnt(2)" ::: "memory");
    } else {
      asm volatile("s_waitcnt vmcnt(0)" ::: "memory");
    }
    __builtin_amdgcn_s_barrier();
    const u16* ks = ksflat + nb * LBUF;
    const u16* vs = vsflat + nb * LBUF;

    bf16x8 bk[4][2];
#pragma unroll
    for (int kb = 0; kb < 4; ++kb) {
      const u16* kr = ks + (kb * 16 + lrow) * 64;
      bk[kb][0] = ld_frag(kr + (lk ^ swz));
      bk[kb][1] = ld_frag(kr + ((32 + lk) ^ swz));
    }

    // QK both q-blocks back-to-back: matrix pipe stays fed while SM(t0)
    // runs on the VALU below
    f32x4 s0[4], s1[4];
    __builtin_amdgcn_s_setprio(1);
#pragma unroll
    for (int kb = 0; kb < 4; ++kb) {
      f32x4 u = {};
      u = __builtin_amdgcn_mfma_f32_16x16x32_bf16(bk[kb][0], aq[0][0], u, 0, 0, 0);
      u = __builtin_amdgcn_mfma_f32_16x16x32_bf16(bk[kb][1], aq[0][1], u, 0, 0, 0);
      s0[kb] = u;
    }
#pragma unroll
    for (int kb = 0; kb < 4; ++kb) {
      f32x4 u = {};
      u = __builtin_amdgcn_mfma_f32_16x16x32_bf16(bk[kb][0], aq[1][0], u, 0, 0, 0);
      u = __builtin_amdgcn_mfma_f32_16x16x32_bf16(bk[kb][1], aq[1][1], u, 0, 0, 0);
      s1[kb] = u;
    }
    __builtin_amdgcn_s_setprio(0);

    bf16x8 ap0[2], ap1[2];
    SM_PACK(s0, ap0[0], ap0[1]);
    SM_PACK(s1, ap1[0], ap1[1]);

#pragma unroll
    for (int kk2 = 0; kk2 < 2; ++kk2) {
      __builtin_amdgcn_s_setprio(1);
#pragma unroll
      for (int cb = 0; cb < 4; ++cb) {
        const u16* vr = vs + (cb * 16 + lrow) * 64;
        bf16x8 bv = ld_frag(vr + ((kk2 * 32 + lk) ^ swz));
        accO[0][cb] = __builtin_amdgcn_mfma_f32_16x16x32_bf16(bv, ap0[kk2], accO[0][cb], 0, 0, 0);
        accO[1][cb] = __builtin_amdgcn_mfma_f32_16x16x32_bf16(bv, ap1[kk2], accO[1][cb], 0, 0, 0);
      }
      acc_ps[0] = __builtin_amdgcn_mfma_f32_16x16x32_bf16(ones, ap0[kk2], acc_ps[0], 0, 0, 0);
      acc_ps[1] = __builtin_amdgcn_mfma_f32_16x16x32_bf16(ones, ap1[kk2], acc_ps[1], 0, 0, 0);
      __builtin_amdgcn_s_setprio(0);
    }

    if (kv0 + 64 < Ls) __builtin_amdgcn_s_barrier();
    nb ^= 1;
  }
#undef SM_PACK

#pragma unroll
  for (int t = 0; t < 2; ++t) {
    float rinv = 1.0f / acc_ps[t][0];
    const size_t orow = (size_t)(rb + q0 + wave * 32 + t * 16 + lrow) * Dd + cb0;
#pragma unroll
    for (int cb = 0; cb < 4; ++cb) {
      uint2 o;
      o.x = cvt_pk_bf16(accO[t][cb][0] * rinv, accO[t][cb][1] * rinv);
      o.y = cvt_pk_bf16(accO[t][cb][2] * rinv, accO[t][cb][3] * rinv);
      *reinterpret_cast<uint2*>(&Om[orow + cb * 16 + (lk >> 1)]) = o;
    }
  }
}

extern "C" void kernel_launch(void* const* d_in, const int* in_sizes, int n_in,
                              void* d_out, int out_size, void* d_ws, size_t ws_size,
                              hipStream_t stream) {
  (void)in_sizes; (void)n_in; (void)out_size; (void)ws_size;
  const float* x  = (const float*)d_in[0];
  const float* wq = (const float*)d_in[1];
  const float* bq = (const float*)d_in[2];
  const float* wk = (const float*)d_in[3];
  const float* bk = (const float*)d_in[4];
  const float* wv = (const float*)d_in[5];
  const float* bv = (const float*)d_in[6];
  const float* wo = (const float*)d_in[7];
  const float* bo = (const float*)d_in[8];
  float* out = (float*)d_out;

  u16* ws  = (u16*)d_ws;
  u16* xb  = ws;
  u16* wqb = xb  + (size_t)Mm * Dd;
  u16* wkb = wqb + (size_t)Dd * Dd;
  u16* wvb = wkb + (size_t)Dd * Dd;
  u16* wob = wvb + (size_t)Dd * Dd;
  u16* qm  = wob + (size_t)Dd * Dd;
  u16* km  = qm  + (size_t)Mm * Dd;
  u16* vt  = km  + (size_t)Mm * Dd;
  u16* om  = xb;

  cvt_all<<<2048, 256, 0, stream>>>(x, wq, wk, wv, wo, xb, wqb, wkb, wvb, wob);

  dim3 qkvgrid(3 * Dd / 256, Mm / 128);   // 12 x 64 = 768 blocks, zero tail
  gemm_qkv<<<qkvgrid, 512, 0, stream>>>(xb, wqb, bq, bk, bv, qm, km, vt);

  dim3 agrid(Bb * Hh, Ls / 256);          // 64 x 8 = 512 blocks, 2/CU
  attn_fwd<<<agrid, 512, 0, stream>>>(qm, km, vt, om);

  dim3 ogrid(Dd / 256, Mm / 128);         // 4 x 64 = 256 blocks, 1/CU
  gemm_out<<<ogrid, 512, 0, stream>>>(om, wob, bo, out);
}